// Round 1
// baseline (8971.477 us; speedup 1.0000x reference)
//
#include <hip/hip_runtime.h>

#define NN 100000
#define NE 1600000
#define CH 128
#define NG 512
#define NL 3

__device__ __forceinline__ long long ld_idx(const void* p, long long i, bool is64) {
    return is64 ? ((const long long*)p)[i] : (long long)((const int*)p)[i];
}

__global__ void k_zero_flags(int* flags) {
    if (threadIdx.x < 2) flags[threadIdx.x] = 0;
}

// Detect int64 vs int32 index arrays: for int64 values < 2^31, every odd
// 32-bit word (within the first n_elem words, present either way) is zero.
__global__ void k_detect(const int* __restrict__ ei32, const int* __restrict__ b32, int* flags) {
    int acc_e = 0, acc_b = 0;
    long long stride = (long long)gridDim.x * blockDim.x;
    long long t0 = (long long)blockIdx.x * blockDim.x + threadIdx.x;
    for (long long i = t0; i < NE; i += stride) acc_e |= ei32[2 * i + 1];
    for (long long i = t0; i < NN / 2; i += stride) acc_b |= b32[2 * i + 1];
    if (acc_e) atomicOr(&flags[0], 1);
    if (acc_b) atomicOr(&flags[1], 1);
}

__global__ void k_deg_init(float* deg) {
    int i = blockIdx.x * blockDim.x + threadIdx.x;
    if (i < NN) deg[i] = 1.0f;   // self-loop
}

__global__ void k_deg(const void* __restrict__ ei, const int* __restrict__ flags, float* deg) {
    long long e = (long long)blockIdx.x * blockDim.x + threadIdx.x;
    if (e >= NE) return;
    bool is64 = (flags[0] == 0);
    long long dst = ld_idx(ei, NE + e, is64);
    atomicAdd(&deg[dst], 1.0f);
}

__global__ void k_dinv(float* deg) {
    int i = blockIdx.x * blockDim.x + threadIdx.x;
    if (i < NN) deg[i] = rsqrtf(deg[i]);   // deg >= 1 always
}

__global__ void k_zero4(float4* p, long long n4) {
    long long stride = (long long)gridDim.x * blockDim.x;
    for (long long i = (long long)blockIdx.x * blockDim.x + threadIdx.x; i < n4; i += stride)
        p[i] = make_float4(0.f, 0.f, 0.f, 0.f);
}

// t = in @ W   (in: [NN,128], W: [128,128] row-major)
// Block: 256 threads, 64 rows/block, K tiled in two halves (48 KB LDS).
__global__ __launch_bounds__(256) void k_gemm(const float* __restrict__ in,
                                              const float* __restrict__ W,
                                              float* __restrict__ out) {
    __shared__ float Wl[64][128];
    __shared__ float hl[64][64];
    int tid = threadIdx.x;
    int r2 = tid >> 7;     // 0..1
    int j  = tid & 127;    // output column
    long long rowBase = (long long)blockIdx.x * 64;

    float acc[32];
#pragma unroll
    for (int r = 0; r < 32; ++r) acc[r] = 0.f;

    for (int kt = 0; kt < 2; ++kt) {
        {   // W tile [64][128] — linear float4 copy
            const float4* Wg = (const float4*)(W + kt * 64 * CH);
            float4* Wl4 = (float4*)&Wl[0][0];
#pragma unroll
            for (int q = 0; q < 8; ++q) Wl4[q * 256 + tid] = Wg[q * 256 + tid];
        }
        {   // h tile [64][64]
            float4* hl4 = (float4*)&hl[0][0];
#pragma unroll
            for (int q = 0; q < 4; ++q) {
                int idx = q * 256 + tid;      // 0..1023 float4s
                int row = idx >> 4;
                int k4  = idx & 15;
                long long grow = rowBase + row;
                float4 v = make_float4(0.f, 0.f, 0.f, 0.f);
                if (grow < NN) v = *(const float4*)(in + grow * CH + kt * 64 + k4 * 4);
                hl4[row * 16 + k4] = v;
            }
        }
        __syncthreads();
        float wreg[64];
#pragma unroll
        for (int k = 0; k < 64; ++k) wreg[k] = Wl[k][j];
#pragma unroll 4
        for (int r = 0; r < 32; ++r) {
            const float4* hp = (const float4*)&hl[r * 2 + r2][0];
#pragma unroll
            for (int k4 = 0; k4 < 16; ++k4) {
                float4 h4 = hp[k4];     // wave-uniform broadcast read
                acc[r] = fmaf(h4.x, wreg[k4 * 4 + 0], acc[r]);
                acc[r] = fmaf(h4.y, wreg[k4 * 4 + 1], acc[r]);
                acc[r] = fmaf(h4.z, wreg[k4 * 4 + 2], acc[r]);
                acc[r] = fmaf(h4.w, wreg[k4 * 4 + 3], acc[r]);
            }
        }
        __syncthreads();
    }
#pragma unroll 4
    for (int r = 0; r < 32; ++r) {
        long long row = rowBase + r * 2 + r2;
        if (row < NN) out[row * CH + j] = acc[r];
    }
}

// Edge scatter: out[dst] += t[src] * dinv[src]*dinv[dst]; 32 threads/edge, float4/thread.
__global__ __launch_bounds__(256) void k_scatter(const void* __restrict__ ei,
                                                 const int* __restrict__ flags,
                                                 const float* __restrict__ t,
                                                 const float* __restrict__ dinv,
                                                 float* __restrict__ out) {
    long long gid = (long long)blockIdx.x * blockDim.x + threadIdx.x;
    long long e = gid >> 5;
    int c = (int)(gid & 31) << 2;
    if (e >= NE) return;
    bool is64 = (flags[0] == 0);
    long long s = ld_idx(ei, e, is64);
    long long d = ld_idx(ei, NE + e, is64);
    float w = dinv[s] * dinv[d];
    float4 v = *(const float4*)(t + s * CH + c);
    float* o = out + d * CH + c;
    atomicAdd(o + 0, v.x * w);
    atomicAdd(o + 1, v.y * w);
    atomicAdd(o + 2, v.z * w);
    atomicAdd(o + 3, v.w * w);
}

// h = relu(acc + t*dinv^2 (self-loop) + bias), in place on acc buffer.
__global__ __launch_bounds__(256) void k_post(const float* __restrict__ accbuf,
                                              const float* __restrict__ t,
                                              const float* __restrict__ dinv,
                                              const float* __restrict__ b,
                                              float* __restrict__ out) {
    long long gid = (long long)blockIdx.x * blockDim.x + threadIdx.x;  // < NN*32
    long long node = gid >> 5;
    int c = (int)(gid & 31) << 2;
    float di = dinv[node];
    float sl = di * di;
    float4 a  = *(const float4*)(accbuf + node * CH + c);
    float4 tv = *(const float4*)(t + node * CH + c);
    float4 bv = *(const float4*)(b + c);
    float4 r;
    r.x = fmaxf(fmaf(tv.x, sl, a.x) + bv.x, 0.f);
    r.y = fmaxf(fmaf(tv.y, sl, a.y) + bv.y, 0.f);
    r.z = fmaxf(fmaf(tv.z, sl, a.z) + bv.z, 0.f);
    r.w = fmaxf(fmaf(tv.w, sl, a.w) + bv.w, 0.f);
    *(float4*)(out + node * CH + c) = r;
}

__global__ void k_out_init(float* out, const float* __restrict__ head_b) {
    int g = blockIdx.x * blockDim.x + threadIdx.x;
    if (g < NG) out[g] = head_b[0];
}

// Fused global_add_pool + head: one wave per node, dot(h[node], head_w) -> atomic.
__global__ __launch_bounds__(256) void k_pool(const float* __restrict__ h,
                                              const void* __restrict__ batch,
                                              const int* __restrict__ flags,
                                              const float* __restrict__ hw,
                                              float* out) {
    long long gid = (long long)blockIdx.x * blockDim.x + threadIdx.x;
    long long node = gid >> 6;
    int lane = (int)(gid & 63);
    if (node >= NN) return;
    float acc = h[node * CH + lane] * hw[lane] + h[node * CH + 64 + lane] * hw[64 + lane];
#pragma unroll
    for (int off = 32; off > 0; off >>= 1) acc += __shfl_down(acc, off);
    if (lane == 0) {
        bool is64 = (flags[1] == 0);
        long long g = ld_idx(batch, node, is64);
        atomicAdd(&out[g], acc);
    }
}

extern "C" void kernel_launch(void* const* d_in, const int* in_sizes, int n_in,
                              void* d_out, int out_size, void* d_ws, size_t ws_size,
                              hipStream_t stream) {
    const float* x  = (const float*)d_in[0];
    const void*  ei = d_in[1];
    const void*  bt = d_in[2];
    const float* Ws = (const float*)d_in[3];
    const float* bs = (const float*)d_in[4];
    const float* hw = (const float*)d_in[5];
    const float* hb = (const float*)d_in[6];
    float* out = (float*)d_out;

    char* ws = (char*)d_ws;
    int*   flags = (int*)ws;                    // 256 B
    float* deg   = (float*)(ws + 256);          // 400 KB
    float* bufA  = (float*)(ws + 400384);       // 51.2 MB (t)
    float* bufB  = bufA + (size_t)NN * CH;      // 51.2 MB (h)

    k_zero_flags<<<1, 64, 0, stream>>>(flags);
    k_detect<<<256, 256, 0, stream>>>((const int*)ei, (const int*)bt, flags);
    k_deg_init<<<(NN + 255) / 256, 256, 0, stream>>>(deg);
    k_deg<<<(NE + 255) / 256, 256, 0, stream>>>(ei, flags, deg);
    k_dinv<<<(NN + 255) / 256, 256, 0, stream>>>(deg);

    const float* hin = x;
    for (int l = 0; l < NL; ++l) {
        k_gemm<<<(NN + 63) / 64, 256, 0, stream>>>(hin, Ws + (size_t)l * CH * CH, bufA);
        k_zero4<<<2048, 256, 0, stream>>>((float4*)bufB, (long long)NN * CH / 4);
        k_scatter<<<(int)(((long long)NE * 32) / 256), 256, 0, stream>>>(ei, flags, bufA, deg, bufB);
        k_post<<<NN * 32 / 256, 256, 0, stream>>>(bufB, bufA, deg, bs + (size_t)l * CH, bufB);
        hin = bufB;
    }
    k_out_init<<<2, 256, 0, stream>>>(out, hb);
    k_pool<<<(int)(((long long)NN * 64) / 256), 256, 0, stream>>>(bufB, bt, flags, hw, out);
}

// Round 2
// 1345.023 us; speedup vs baseline: 6.6701x; 6.6701x over previous
//
#include <hip/hip_runtime.h>

#define NN 100000
#define NE 1600000
#define CH 128
#define NG 512
#define NL 3

__device__ __forceinline__ long long ld_idx(const void* p, long long i, bool is64) {
    return is64 ? ((const long long*)p)[i] : (long long)((const int*)p)[i];
}

__global__ void k_zero_flags(int* flags) {
    if (threadIdx.x < 2) flags[threadIdx.x] = 0;
}

// Detect int64 vs int32 index arrays: for int64 values < 2^31, every odd
// 32-bit word (within the first n_elem words, present either way) is zero.
__global__ void k_detect(const int* __restrict__ ei32, const int* __restrict__ b32, int* flags) {
    int acc_e = 0, acc_b = 0;
    long long stride = (long long)gridDim.x * blockDim.x;
    long long t0 = (long long)blockIdx.x * blockDim.x + threadIdx.x;
    for (long long i = t0; i < NE; i += stride) acc_e |= ei32[2 * i + 1];
    for (long long i = t0; i < NN / 2; i += stride) acc_b |= b32[2 * i + 1];
    if (acc_e) atomicOr(&flags[0], 1);
    if (acc_b) atomicOr(&flags[1], 1);
}

// ---------------- CSR build path ----------------

__global__ void k_zeroi(int* p, int n) {
    int i = blockIdx.x * blockDim.x + threadIdx.x;
    if (i < n) p[i] = 0;
}

__global__ void k_count(const void* __restrict__ ei, const int* __restrict__ flags,
                        int* __restrict__ indeg) {
    int e = blockIdx.x * blockDim.x + threadIdx.x;
    if (e >= NE) return;
    bool is64 = (flags[0] == 0);
    int d = (int)ld_idx(ei, (long long)NE + e, is64);
    atomicAdd(&indeg[d], 1);
}

// exclusive scan, stage 1: per-block (256) scan -> rowptr[i] (local excl), bsum[b]
__global__ __launch_bounds__(256) void k_scan1(const int* __restrict__ indeg,
                                               int* __restrict__ rowptr,
                                               int* __restrict__ bsum) {
    __shared__ int ws4[4];
    int t = threadIdx.x;
    int i = blockIdx.x * 256 + t;
    int v = (i < NN) ? indeg[i] : 0;
    int x = v;
#pragma unroll
    for (int d = 1; d < 64; d <<= 1) {
        int y = __shfl_up(x, d, 64);
        if ((t & 63) >= d) x += y;
    }
    if ((t & 63) == 63) ws4[t >> 6] = x;
    __syncthreads();
    if (t == 0) {
        int s = 0;
#pragma unroll
        for (int w = 0; w < 4; ++w) { int tmp = ws4[w]; ws4[w] = s; s += tmp; }
        bsum[blockIdx.x] = s;
    }
    __syncthreads();
    if (i < NN) rowptr[i] = x - v + ws4[t >> 6];
}

// stage 2: exclusive scan of block sums (nb <= 512), one block
__global__ __launch_bounds__(512) void k_scan2(int* __restrict__ bsum, int nb) {
    __shared__ int ws8[8];
    int t = threadIdx.x;
    int v = (t < nb) ? bsum[t] : 0;
    int x = v;
#pragma unroll
    for (int d = 1; d < 64; d <<= 1) {
        int y = __shfl_up(x, d, 64);
        if ((t & 63) >= d) x += y;
    }
    if ((t & 63) == 63) ws8[t >> 6] = x;
    __syncthreads();
    if (t == 0) {
        int s = 0;
#pragma unroll
        for (int w = 0; w < 8; ++w) { int tmp = ws8[w]; ws8[w] = s; s += tmp; }
    }
    __syncthreads();
    if (t < nb) bsum[t] = x - v + ws8[t >> 6];
}

// stage 3: add block base; init cursor; rowptr[NN] = NE
__global__ void k_scan3(int* __restrict__ rowptr, const int* __restrict__ bsum,
                        int* __restrict__ cursor) {
    int i = blockIdx.x * 256 + threadIdx.x;
    if (i < NN) {
        int r = rowptr[i] + bsum[blockIdx.x];
        rowptr[i] = r;
        cursor[i] = r;
    }
    if (i == 0) rowptr[NN] = NE;
}

__global__ void k_dinv_i(const int* __restrict__ indeg, float* __restrict__ dinv) {
    int i = blockIdx.x * blockDim.x + threadIdx.x;
    if (i < NN) dinv[i] = rsqrtf((float)indeg[i] + 1.0f);
}

__global__ void k_fill(const void* __restrict__ ei, const int* __restrict__ flags,
                       int* __restrict__ cursor, int* __restrict__ csr_src) {
    int e = blockIdx.x * blockDim.x + threadIdx.x;
    if (e >= NE) return;
    bool is64 = (flags[0] == 0);
    int s = (int)ld_idx(ei, e, is64);
    int d = (int)ld_idx(ei, (long long)NE + e, is64);
    int pos = atomicAdd(&cursor[d], 1);
    csr_src[pos] = s;
}

// Gather aggregation: one wave per node, 2 ch/lane. h = relu(sum + self + b).
__global__ __launch_bounds__(256) void k_aggr(const float* __restrict__ t,
                                              const int* __restrict__ rowptr,
                                              const int* __restrict__ csr_src,
                                              const float* __restrict__ dinv,
                                              const float* __restrict__ b,
                                              float* __restrict__ h) {
    int node = (blockIdx.x << 2) + (threadIdx.x >> 6);
    if (node >= NN) return;
    int lane = threadIdx.x & 63;
    int c = lane << 1;
    int beg = rowptr[node], end = rowptr[node + 1];
    float dn = dinv[node];
    float2 tv = *(const float2*)(t + (size_t)node * CH + c);
    float sl = dn * dn;
    float a0 = tv.x * sl, a1 = tv.y * sl;
    int e = beg;
    for (; e + 4 <= end; e += 4) {
        int s0 = csr_src[e], s1 = csr_src[e + 1], s2 = csr_src[e + 2], s3 = csr_src[e + 3];
        float w0 = dinv[s0] * dn, w1 = dinv[s1] * dn;
        float w2 = dinv[s2] * dn, w3 = dinv[s3] * dn;
        float2 v0 = *(const float2*)(t + (size_t)s0 * CH + c);
        float2 v1 = *(const float2*)(t + (size_t)s1 * CH + c);
        float2 v2 = *(const float2*)(t + (size_t)s2 * CH + c);
        float2 v3 = *(const float2*)(t + (size_t)s3 * CH + c);
        a0 = fmaf(v0.x, w0, a0); a1 = fmaf(v0.y, w0, a1);
        a0 = fmaf(v1.x, w1, a0); a1 = fmaf(v1.y, w1, a1);
        a0 = fmaf(v2.x, w2, a0); a1 = fmaf(v2.y, w2, a1);
        a0 = fmaf(v3.x, w3, a0); a1 = fmaf(v3.y, w3, a1);
    }
    for (; e < end; ++e) {
        int s = csr_src[e];
        float w = dinv[s] * dn;
        float2 v = *(const float2*)(t + (size_t)s * CH + c);
        a0 = fmaf(v.x, w, a0); a1 = fmaf(v.y, w, a1);
    }
    float2 bv = *(const float2*)(b + c);
    float2 r;
    r.x = fmaxf(a0 + bv.x, 0.f);
    r.y = fmaxf(a1 + bv.y, 0.f);
    *(float2*)(h + (size_t)node * CH + c) = r;
}

// ---------------- fallback (atomic scatter) path ----------------

__global__ void k_zero4(float4* p, long long n4) {
    long long stride = (long long)gridDim.x * blockDim.x;
    for (long long i = (long long)blockIdx.x * blockDim.x + threadIdx.x; i < n4; i += stride)
        p[i] = make_float4(0.f, 0.f, 0.f, 0.f);
}

__global__ __launch_bounds__(256) void k_scatter(const void* __restrict__ ei,
                                                 const int* __restrict__ flags,
                                                 const float* __restrict__ t,
                                                 const float* __restrict__ dinv,
                                                 float* __restrict__ out) {
    long long gid = (long long)blockIdx.x * blockDim.x + threadIdx.x;
    long long e = gid >> 5;
    int c = (int)(gid & 31) << 2;
    if (e >= NE) return;
    bool is64 = (flags[0] == 0);
    long long s = ld_idx(ei, e, is64);
    long long d = ld_idx(ei, NE + e, is64);
    float w = dinv[s] * dinv[d];
    float4 v = *(const float4*)(t + s * CH + c);
    float* o = out + d * CH + c;
    atomicAdd(o + 0, v.x * w);
    atomicAdd(o + 1, v.y * w);
    atomicAdd(o + 2, v.z * w);
    atomicAdd(o + 3, v.w * w);
}

__global__ __launch_bounds__(256) void k_post(const float* __restrict__ accbuf,
                                              const float* __restrict__ t,
                                              const float* __restrict__ dinv,
                                              const float* __restrict__ b,
                                              float* __restrict__ out) {
    long long gid = (long long)blockIdx.x * blockDim.x + threadIdx.x;
    long long node = gid >> 5;
    int c = (int)(gid & 31) << 2;
    float di = dinv[node];
    float sl = di * di;
    float4 a  = *(const float4*)(accbuf + node * CH + c);
    float4 tv = *(const float4*)(t + node * CH + c);
    float4 bv = *(const float4*)(b + c);
    float4 r;
    r.x = fmaxf(fmaf(tv.x, sl, a.x) + bv.x, 0.f);
    r.y = fmaxf(fmaf(tv.y, sl, a.y) + bv.y, 0.f);
    r.z = fmaxf(fmaf(tv.z, sl, a.z) + bv.z, 0.f);
    r.w = fmaxf(fmaf(tv.w, sl, a.w) + bv.w, 0.f);
    *(float4*)(out + node * CH + c) = r;
}

// ---------------- GEMM ----------------

__global__ __launch_bounds__(256) void k_gemm(const float* __restrict__ in,
                                              const float* __restrict__ W,
                                              float* __restrict__ out) {
    __shared__ float Wl[64][128];
    __shared__ float hl[64][64];
    int tid = threadIdx.x;
    int r2 = tid >> 7;
    int j  = tid & 127;
    long long rowBase = (long long)blockIdx.x * 64;

    float acc[32];
#pragma unroll
    for (int r = 0; r < 32; ++r) acc[r] = 0.f;

    for (int kt = 0; kt < 2; ++kt) {
        {
            const float4* Wg = (const float4*)(W + kt * 64 * CH);
            float4* Wl4 = (float4*)&Wl[0][0];
#pragma unroll
            for (int q = 0; q < 8; ++q) Wl4[q * 256 + tid] = Wg[q * 256 + tid];
        }
        {
            float4* hl4 = (float4*)&hl[0][0];
#pragma unroll
            for (int q = 0; q < 4; ++q) {
                int idx = q * 256 + tid;
                int row = idx >> 4;
                int k4  = idx & 15;
                long long grow = rowBase + row;
                float4 v = make_float4(0.f, 0.f, 0.f, 0.f);
                if (grow < NN) v = *(const float4*)(in + grow * CH + kt * 64 + k4 * 4);
                hl4[row * 16 + k4] = v;
            }
        }
        __syncthreads();
        float wreg[64];
#pragma unroll
        for (int k = 0; k < 64; ++k) wreg[k] = Wl[k][j];
#pragma unroll 4
        for (int r = 0; r < 32; ++r) {
            const float4* hp = (const float4*)&hl[r * 2 + r2][0];
#pragma unroll
            for (int k4 = 0; k4 < 16; ++k4) {
                float4 h4 = hp[k4];
                acc[r] = fmaf(h4.x, wreg[k4 * 4 + 0], acc[r]);
                acc[r] = fmaf(h4.y, wreg[k4 * 4 + 1], acc[r]);
                acc[r] = fmaf(h4.z, wreg[k4 * 4 + 2], acc[r]);
                acc[r] = fmaf(h4.w, wreg[k4 * 4 + 3], acc[r]);
            }
        }
        __syncthreads();
    }
#pragma unroll 4
    for (int r = 0; r < 32; ++r) {
        long long row = rowBase + r * 2 + r2;
        if (row < NN) out[row * CH + j] = acc[r];
    }
}

// ---------------- pooling + head ----------------

__global__ void k_out_init(float* out, const float* __restrict__ head_b) {
    int g = blockIdx.x * blockDim.x + threadIdx.x;
    if (g < NG) out[g] = head_b[0];
}

__global__ __launch_bounds__(256) void k_pool(const float* __restrict__ h,
                                              const void* __restrict__ batch,
                                              const int* __restrict__ flags,
                                              const float* __restrict__ hw,
                                              float* out) {
    long long gid = (long long)blockIdx.x * blockDim.x + threadIdx.x;
    long long node = gid >> 6;
    int lane = (int)(gid & 63);
    if (node >= NN) return;
    float acc = h[node * CH + lane] * hw[lane] + h[node * CH + 64 + lane] * hw[64 + lane];
#pragma unroll
    for (int off = 32; off > 0; off >>= 1) acc += __shfl_down(acc, off);
    if (lane == 0) {
        bool is64 = (flags[1] == 0);
        long long g = ld_idx(batch, node, is64);
        atomicAdd(&out[g], acc);
    }
}

extern "C" void kernel_launch(void* const* d_in, const int* in_sizes, int n_in,
                              void* d_out, int out_size, void* d_ws, size_t ws_size,
                              hipStream_t stream) {
    const float* x  = (const float*)d_in[0];
    const void*  ei = d_in[1];
    const void*  bt = d_in[2];
    const float* Ws = (const float*)d_in[3];
    const float* bs = (const float*)d_in[4];
    const float* hw = (const float*)d_in[5];
    const float* hb = (const float*)d_in[6];
    float* out = (float*)d_out;

    char* ws = (char*)d_ws;
    size_t p = 0;
    auto alloc = [&](size_t bytes) { size_t r = p; p += (bytes + 255) & ~(size_t)255; return r; };
    size_t o_flags  = alloc(256);
    size_t o_dinv   = alloc((size_t)NN * 4);
    size_t o_indeg  = alloc((size_t)NN * 4);
    size_t o_rowptr = alloc((size_t)(NN + 1) * 4);
    size_t o_cursor = alloc((size_t)NN * 4);
    size_t o_bsum   = alloc(512 * 4);
    size_t o_csr    = alloc((size_t)NE * 4);
    size_t o_bufA   = alloc((size_t)NN * CH * 4);
    size_t o_bufB   = alloc((size_t)NN * CH * 4);
    bool csr_ok = (ws_size >= p);

    int*   flags = (int*)(ws + o_flags);
    float* dinv  = (float*)(ws + o_dinv);
    float* bufA, *bufB;

    k_zero_flags<<<1, 64, 0, stream>>>(flags);
    k_detect<<<256, 256, 0, stream>>>((const int*)ei, (const int*)bt, flags);

    const int nb = (NN + 255) / 256;   // 391

    if (csr_ok) {
        int* indeg  = (int*)(ws + o_indeg);
        int* rowptr = (int*)(ws + o_rowptr);
        int* cursor = (int*)(ws + o_cursor);
        int* bsum   = (int*)(ws + o_bsum);
        int* csr    = (int*)(ws + o_csr);
        bufA = (float*)(ws + o_bufA);
        bufB = (float*)(ws + o_bufB);

        k_zeroi<<<nb, 256, 0, stream>>>(indeg, NN);
        k_count<<<(NE + 255) / 256, 256, 0, stream>>>(ei, flags, indeg);
        k_scan1<<<nb, 256, 0, stream>>>(indeg, rowptr, bsum);
        k_scan2<<<1, 512, 0, stream>>>(bsum, nb);
        k_scan3<<<nb, 256, 0, stream>>>(rowptr, bsum, cursor);
        k_dinv_i<<<nb, 256, 0, stream>>>(indeg, dinv);
        k_fill<<<(NE + 255) / 256, 256, 0, stream>>>(ei, flags, cursor, csr);

        const float* hin = x;
        for (int l = 0; l < NL; ++l) {
            k_gemm<<<(NN + 63) / 64, 256, 0, stream>>>(hin, Ws + (size_t)l * CH * CH, bufA);
            k_aggr<<<(NN + 3) / 4, 256, 0, stream>>>(bufA, rowptr, csr, dinv,
                                                     bs + (size_t)l * CH, bufB);
            hin = bufB;
        }
    } else {
        // fallback: atomic scatter (fits in ~103 MB)
        float* deg = (float*)(ws + o_dinv);
        bufA = (float*)(ws + 400384);
        bufB = bufA + (size_t)NN * CH;
        // integer-free degree: count via float atomics as in R1
        k_zeroi<<<nb, 256, 0, stream>>>((int*)deg, NN);
        k_count<<<(NE + 255) / 256, 256, 0, stream>>>(ei, flags, (int*)deg);
        k_dinv_i<<<nb, 256, 0, stream>>>((const int*)deg, deg);

        const float* hin = x;
        for (int l = 0; l < NL; ++l) {
            k_gemm<<<(NN + 63) / 64, 256, 0, stream>>>(hin, Ws + (size_t)l * CH * CH, bufA);
            k_zero4<<<2048, 256, 0, stream>>>((float4*)bufB, (long long)NN * CH / 4);
            k_scatter<<<(int)(((long long)NE * 32) / 256), 256, 0, stream>>>(ei, flags, bufA, deg, bufB);
            k_post<<<NN * 32 / 256, 256, 0, stream>>>(bufB, bufA, deg, bs + (size_t)l * CH, bufB);
            hin = bufB;
        }
    }

    k_out_init<<<2, 256, 0, stream>>>(out, hb);
    k_pool<<<(int)(((long long)NN * 64) / 256), 256, 0, stream>>>(bufB, bt, flags, hw, out);
}

// Round 3
// 702.024 us; speedup vs baseline: 12.7794x; 1.9159x over previous
//
#include <hip/hip_runtime.h>

#define NN 100000
#define NE 1600000
#define CH 128
#define NG 512
#define NL 3

typedef short bf8 __attribute__((ext_vector_type(8)));
typedef float f4 __attribute__((ext_vector_type(4)));
typedef unsigned short u16;
typedef unsigned int u32;

__device__ __forceinline__ long long ld_idx(const void* p, long long i, bool is64) {
    return is64 ? ((const long long*)p)[i] : (long long)((const int*)p)[i];
}
__device__ __forceinline__ u16 f2bf(float f) {
    u32 u = __float_as_uint(f);
    u += 0x7fffu + ((u >> 16) & 1u);
    return (u16)(u >> 16);
}
__device__ __forceinline__ float bflo(u32 v) { return __uint_as_float(v << 16); }
__device__ __forceinline__ float bfhi(u32 v) { return __uint_as_float(v & 0xffff0000u); }

__global__ void k_zero_flags(int* flags) {
    if (threadIdx.x < 2) flags[threadIdx.x] = 0;
}

// Detect int64 vs int32 index arrays: for int64 values < 2^31, every odd
// 32-bit word (within the first n_elem words, present either way) is zero.
__global__ void k_detect(const int* __restrict__ ei32, const int* __restrict__ b32, int* flags) {
    int acc_e = 0, acc_b = 0;
    long long stride = (long long)gridDim.x * blockDim.x;
    long long t0 = (long long)blockIdx.x * blockDim.x + threadIdx.x;
    for (long long i = t0; i < NE; i += stride) acc_e |= ei32[2 * i + 1];
    for (long long i = t0; i < NN / 2; i += stride) acc_b |= b32[2 * i + 1];
    if (acc_e) atomicOr(&flags[0], 1);
    if (acc_b) atomicOr(&flags[1], 1);
}

// ---------------- CSR build ----------------

__global__ void k_zeroi(int* p, int n) {
    int i = blockIdx.x * blockDim.x + threadIdx.x;
    if (i < n) p[i] = 0;
}

__global__ void k_count(const void* __restrict__ ei, const int* __restrict__ flags,
                        int* __restrict__ indeg) {
    int e = blockIdx.x * blockDim.x + threadIdx.x;
    if (e >= NE) return;
    bool is64 = (flags[0] == 0);
    int d = (int)ld_idx(ei, (long long)NE + e, is64);
    atomicAdd(&indeg[d], 1);
}

__global__ __launch_bounds__(256) void k_scan1(const int* __restrict__ indeg,
                                               int* __restrict__ rowptr,
                                               int* __restrict__ bsum) {
    __shared__ int ws4[4];
    int t = threadIdx.x;
    int i = blockIdx.x * 256 + t;
    int v = (i < NN) ? indeg[i] : 0;
    int x = v;
#pragma unroll
    for (int d = 1; d < 64; d <<= 1) {
        int y = __shfl_up(x, d, 64);
        if ((t & 63) >= d) x += y;
    }
    if ((t & 63) == 63) ws4[t >> 6] = x;
    __syncthreads();
    if (t == 0) {
        int s = 0;
#pragma unroll
        for (int w = 0; w < 4; ++w) { int tmp = ws4[w]; ws4[w] = s; s += tmp; }
        bsum[blockIdx.x] = s;
    }
    __syncthreads();
    if (i < NN) rowptr[i] = x - v + ws4[t >> 6];
}

__global__ __launch_bounds__(512) void k_scan2(int* __restrict__ bsum, int nb) {
    __shared__ int ws8[8];
    int t = threadIdx.x;
    int v = (t < nb) ? bsum[t] : 0;
    int x = v;
#pragma unroll
    for (int d = 1; d < 64; d <<= 1) {
        int y = __shfl_up(x, d, 64);
        if ((t & 63) >= d) x += y;
    }
    if ((t & 63) == 63) ws8[t >> 6] = x;
    __syncthreads();
    if (t == 0) {
        int s = 0;
#pragma unroll
        for (int w = 0; w < 8; ++w) { int tmp = ws8[w]; ws8[w] = s; s += tmp; }
    }
    __syncthreads();
    if (t < nb) bsum[t] = x - v + ws8[t >> 6];
}

__global__ void k_scan3(int* __restrict__ rowptr, const int* __restrict__ bsum,
                        int* __restrict__ cursor) {
    int i = blockIdx.x * 256 + threadIdx.x;
    if (i < NN) {
        int r = rowptr[i] + bsum[blockIdx.x];
        rowptr[i] = r;
        cursor[i] = r;
    }
    if (i == 0) rowptr[NN] = NE;
}

__global__ void k_dinv_i(const int* __restrict__ indeg, float* __restrict__ dinv) {
    int i = blockIdx.x * blockDim.x + threadIdx.x;
    if (i < NN) dinv[i] = rsqrtf((float)indeg[i] + 1.0f);
}

// fill CSR with packed (src, weight)
__global__ void k_fill(const void* __restrict__ ei, const int* __restrict__ flags,
                       const float* __restrict__ dinv,
                       int* __restrict__ cursor, int2* __restrict__ csrp) {
    int e = blockIdx.x * blockDim.x + threadIdx.x;
    if (e >= NE) return;
    bool is64 = (flags[0] == 0);
    int s = (int)ld_idx(ei, e, is64);
    int d = (int)ld_idx(ei, (long long)NE + e, is64);
    int pos = atomicAdd(&cursor[d], 1);
    float w = dinv[s] * dinv[d];
    csrp[pos] = make_int2(s, __float_as_int(w));
}

// ---------------- bf16 conversion ----------------

__global__ void k_cvt_x(const float* __restrict__ x, u16* __restrict__ xb) {
    long long i = ((long long)blockIdx.x * blockDim.x + threadIdx.x) * 4;
    if (i >= (long long)NN * CH) return;
    float4 v = *(const float4*)(x + i);
    ushort4 o;
    o.x = f2bf(v.x); o.y = f2bf(v.y); o.z = f2bf(v.z); o.w = f2bf(v.w);
    *(ushort4*)(xb + i) = o;
}

// Wt[l][c][k] = bf16(Ws[l][k][c])
__global__ void k_cvt_w(const float* __restrict__ Ws, u16* __restrict__ Wt) {
    int i = blockIdx.x * blockDim.x + threadIdx.x;
    if (i >= NL * CH * CH) return;
    int l = i >> 14;
    int c = (i >> 7) & 127;
    int k = i & 127;
    Wt[i] = f2bf(Ws[(l << 14) + (k << 7) + c]);
}

// ---------------- MFMA GEMM: out[N,128] = A[N,128] @ W, all bf16 ----------------
// No LDS: A-frag and B-frag are contiguous 16B global loads.
// 16x16x32 layout: A lane holds A[lane&15][(lane>>4)*8 + j];
//                  B lane holds B[(lane>>4)*8 + j][lane&15]  (= rows of W^T);
//                  C lane reg r -> row=(lane>>4)*4+r, col=lane&15.
__global__ __launch_bounds__(256) void k_mm(const u16* __restrict__ A,
                                            const u16* __restrict__ Wt,
                                            u16* __restrict__ out) {
    int tid = threadIdx.x;
    int lane = tid & 63;
    int wv = tid >> 6;
    int rbase = blockIdx.x * 128 + wv * 32;
    int lm = lane & 15;
    int lk = (lane >> 4) << 3;

    f4 acc[2][8];
#pragma unroll
    for (int m = 0; m < 2; ++m)
#pragma unroll
        for (int n = 0; n < 8; ++n) acc[m][n] = (f4){0.f, 0.f, 0.f, 0.f};

    int r0 = rbase + lm;      if (r0 >= NN) r0 = NN - 1;
    int r1 = rbase + 16 + lm; if (r1 >= NN) r1 = NN - 1;

#pragma unroll
    for (int kk = 0; kk < 4; ++kk) {
        int ko = kk * 32 + lk;
        bf8 a0 = *(const bf8*)(A + (size_t)r0 * CH + ko);
        bf8 a1 = *(const bf8*)(A + (size_t)r1 * CH + ko);
#pragma unroll
        for (int n = 0; n < 8; ++n) {
            bf8 b = *(const bf8*)(Wt + (n * 16 + lm) * CH + ko);
            acc[0][n] = __builtin_amdgcn_mfma_f32_16x16x32_bf16(a0, b, acc[0][n], 0, 0, 0);
            acc[1][n] = __builtin_amdgcn_mfma_f32_16x16x32_bf16(a1, b, acc[1][n], 0, 0, 0);
        }
    }

#pragma unroll
    for (int m = 0; m < 2; ++m) {
        int rb = rbase + m * 16 + (lane >> 4) * 4;
#pragma unroll
        for (int r = 0; r < 4; ++r) {
            int row = rb + r;
            if (row < NN) {
#pragma unroll
                for (int n = 0; n < 8; ++n)
                    out[(size_t)row * CH + n * 16 + lm] = f2bf(acc[m][n][r]);
            }
        }
    }
}

// ---------------- aggregation: gather + self + bias + relu -> bf16 h ----------------
__global__ __launch_bounds__(256) void k_aggr(const u16* __restrict__ t,
                                              const int* __restrict__ rowptr,
                                              const int2* __restrict__ csrp,
                                              const float* __restrict__ dinv,
                                              const float* __restrict__ b,
                                              u16* __restrict__ h) {
    int node = (blockIdx.x << 2) + (threadIdx.x >> 6);
    if (node >= NN) return;
    int lane = threadIdx.x & 63;
    int c = lane << 1;
    int beg = rowptr[node], end = rowptr[node + 1];
    float dn = dinv[node];
    u32 sv = *(const u32*)(t + (size_t)node * CH + c);
    float sl = dn * dn;
    float a0 = bflo(sv) * sl, a1 = bfhi(sv) * sl;

    for (int base = beg; base < end; base += 64) {
        int2 pk = make_int2(0, 0);
        if (base + lane < end) pk = csrp[base + lane];
        int cnt = min(64, end - base);
        int j = 0;
        for (; j + 4 <= cnt; j += 4) {
            int s0 = __shfl(pk.x, j),     s1 = __shfl(pk.x, j + 1);
            int s2 = __shfl(pk.x, j + 2), s3 = __shfl(pk.x, j + 3);
            float w0 = __uint_as_float((u32)__shfl(pk.y, j));
            float w1 = __uint_as_float((u32)__shfl(pk.y, j + 1));
            float w2 = __uint_as_float((u32)__shfl(pk.y, j + 2));
            float w3 = __uint_as_float((u32)__shfl(pk.y, j + 3));
            u32 t0 = *(const u32*)(t + (size_t)s0 * CH + c);
            u32 t1 = *(const u32*)(t + (size_t)s1 * CH + c);
            u32 t2 = *(const u32*)(t + (size_t)s2 * CH + c);
            u32 t3 = *(const u32*)(t + (size_t)s3 * CH + c);
            a0 = fmaf(bflo(t0), w0, a0); a1 = fmaf(bfhi(t0), w0, a1);
            a0 = fmaf(bflo(t1), w1, a0); a1 = fmaf(bfhi(t1), w1, a1);
            a0 = fmaf(bflo(t2), w2, a0); a1 = fmaf(bfhi(t2), w2, a1);
            a0 = fmaf(bflo(t3), w3, a0); a1 = fmaf(bfhi(t3), w3, a1);
        }
        for (; j < cnt; ++j) {
            int s = __shfl(pk.x, j);
            float w = __uint_as_float((u32)__shfl(pk.y, j));
            u32 tv = *(const u32*)(t + (size_t)s * CH + c);
            a0 = fmaf(bflo(tv), w, a0); a1 = fmaf(bfhi(tv), w, a1);
        }
    }
    float2 bv = *(const float2*)(b + c);
    float r0 = fmaxf(a0 + bv.x, 0.f);
    float r1 = fmaxf(a1 + bv.y, 0.f);
    *(u32*)(h + (size_t)node * CH + c) = ((u32)f2bf(r1) << 16) | (u32)f2bf(r0);
}

// ---------------- pooling + head ----------------

__global__ void k_out_init(float* out, const float* __restrict__ head_b) {
    int g = blockIdx.x * blockDim.x + threadIdx.x;
    if (g < NG) out[g] = head_b[0];
}

__global__ __launch_bounds__(256) void k_pool(const u16* __restrict__ h,
                                              const void* __restrict__ batch,
                                              const int* __restrict__ flags,
                                              const float* __restrict__ hw,
                                              float* out) {
    long long gid = (long long)blockIdx.x * blockDim.x + threadIdx.x;
    long long node = gid >> 6;
    int lane = (int)(gid & 63);
    if (node >= NN) return;
    u32 v = *(const u32*)(h + node * CH + lane * 2);
    float2 wv = *(const float2*)(hw + lane * 2);
    float acc = bflo(v) * wv.x + bfhi(v) * wv.y;
#pragma unroll
    for (int off = 32; off > 0; off >>= 1) acc += __shfl_down(acc, off);
    if (lane == 0) {
        bool is64 = (flags[1] == 0);
        long long g = ld_idx(batch, node, is64);
        atomicAdd(&out[g], acc);
    }
}

extern "C" void kernel_launch(void* const* d_in, const int* in_sizes, int n_in,
                              void* d_out, int out_size, void* d_ws, size_t ws_size,
                              hipStream_t stream) {
    const float* x  = (const float*)d_in[0];
    const void*  ei = d_in[1];
    const void*  bt = d_in[2];
    const float* Ws = (const float*)d_in[3];
    const float* bs = (const float*)d_in[4];
    const float* hw = (const float*)d_in[5];
    const float* hb = (const float*)d_in[6];
    float* out = (float*)d_out;

    char* ws = (char*)d_ws;
    size_t p = 0;
    auto alloc = [&](size_t bytes) { size_t r = p; p += (bytes + 255) & ~(size_t)255; return r; };
    size_t o_flags  = alloc(256);
    size_t o_dinv   = alloc((size_t)NN * 4);
    size_t o_indeg  = alloc((size_t)NN * 4);
    size_t o_rowptr = alloc((size_t)(NN + 1) * 4);
    size_t o_cursor = alloc((size_t)NN * 4);
    size_t o_bsum   = alloc(512 * 4);
    size_t o_csrp   = alloc((size_t)NE * 8);
    size_t o_xb     = alloc((size_t)NN * CH * 2);
    size_t o_tb     = alloc((size_t)NN * CH * 2);
    size_t o_hb     = alloc((size_t)NN * CH * 2);
    size_t o_wt     = alloc((size_t)NL * CH * CH * 2);
    (void)ws_size;  // ~66 MB, fits (R2 used ~111 MB)

    int*   flags  = (int*)(ws + o_flags);
    float* dinv   = (float*)(ws + o_dinv);
    int*   indeg  = (int*)(ws + o_indeg);
    int*   rowptr = (int*)(ws + o_rowptr);
    int*   cursor = (int*)(ws + o_cursor);
    int*   bsum   = (int*)(ws + o_bsum);
    int2*  csrp   = (int2*)(ws + o_csrp);
    u16*   xb     = (u16*)(ws + o_xb);
    u16*   tb     = (u16*)(ws + o_tb);
    u16*   hbuf   = (u16*)(ws + o_hb);
    u16*   Wt     = (u16*)(ws + o_wt);

    const int nb = (NN + 255) / 256;   // 391

    k_zero_flags<<<1, 64, 0, stream>>>(flags);
    k_detect<<<256, 256, 0, stream>>>((const int*)ei, (const int*)bt, flags);

    k_zeroi<<<nb, 256, 0, stream>>>(indeg, NN);
    k_count<<<(NE + 255) / 256, 256, 0, stream>>>(ei, flags, indeg);
    k_scan1<<<nb, 256, 0, stream>>>(indeg, rowptr, bsum);
    k_scan2<<<1, 512, 0, stream>>>(bsum, nb);
    k_scan3<<<nb, 256, 0, stream>>>(rowptr, bsum, cursor);
    k_dinv_i<<<nb, 256, 0, stream>>>(indeg, dinv);
    k_fill<<<(NE + 255) / 256, 256, 0, stream>>>(ei, flags, dinv, cursor, csrp);

    k_cvt_x<<<(int)(((long long)NN * CH / 4 + 255) / 256), 256, 0, stream>>>(x, xb);
    k_cvt_w<<<(NL * CH * CH + 255) / 256, 256, 0, stream>>>(Ws, Wt);

    const u16* hin = xb;
    for (int l = 0; l < NL; ++l) {
        k_mm<<<(NN + 127) / 128, 256, 0, stream>>>(hin, Wt + (size_t)l * CH * CH, tb);
        k_aggr<<<(NN + 3) / 4, 256, 0, stream>>>(tb, rowptr, csrp, dinv,
                                                 bs + (size_t)l * CH, hbuf);
        hin = hbuf;
    }

    k_out_init<<<2, 256, 0, stream>>>(out, hb);
    k_pool<<<(int)(((long long)NN * 64) / 256), 256, 0, stream>>>(hbuf, bt, flags, hw, out);
}

// Round 4
// 492.017 us; speedup vs baseline: 18.2341x; 1.4268x over previous
//
#include <hip/hip_runtime.h>

#define NN 100000
#define NE 1600000
#define CH 128
#define NG 512
#define NL 3

typedef short bf8 __attribute__((ext_vector_type(8)));
typedef float f4 __attribute__((ext_vector_type(4)));
typedef unsigned short u16;
typedef unsigned int u32;

__device__ __forceinline__ long long ld_idx(const void* p, long long i, bool is64) {
    return is64 ? ((const long long*)p)[i] : (long long)((const int*)p)[i];
}
__device__ __forceinline__ u16 f2bf(float f) {
    u32 u = __float_as_uint(f);
    u += 0x7fffu + ((u >> 16) & 1u);
    return (u16)(u >> 16);
}
__device__ __forceinline__ float bflo(u32 v) { return __uint_as_float(v << 16); }
__device__ __forceinline__ float bfhi(u32 v) { return __uint_as_float(v & 0xffff0000u); }

__global__ void k_zero_flags(int* flags) {
    if (threadIdx.x < 2) flags[threadIdx.x] = 0;
}

// Detect int64 vs int32 index arrays: for int64 values < 2^31, every odd
// 32-bit word (within the first n_elem words, present either way) is zero.
__global__ void k_detect(const int* __restrict__ ei32, const int* __restrict__ b32, int* flags) {
    int acc_e = 0, acc_b = 0;
    long long stride = (long long)gridDim.x * blockDim.x;
    long long t0 = (long long)blockIdx.x * blockDim.x + threadIdx.x;
    for (long long i = t0; i < NE; i += stride) acc_e |= ei32[2 * i + 1];
    for (long long i = t0; i < NN / 2; i += stride) acc_b |= b32[2 * i + 1];
    if (acc_e) atomicOr(&flags[0], 1);
    if (acc_b) atomicOr(&flags[1], 1);
}

// ---------------- CSR build ----------------

__global__ void k_zeroi(int* p, int n) {
    int i = blockIdx.x * blockDim.x + threadIdx.x;
    if (i < n) p[i] = 0;
}

__global__ void k_count(const void* __restrict__ ei, const int* __restrict__ flags,
                        int* __restrict__ indeg) {
    int e = blockIdx.x * blockDim.x + threadIdx.x;
    if (e >= NE) return;
    bool is64 = (flags[0] == 0);
    int d = (int)ld_idx(ei, (long long)NE + e, is64);
    atomicAdd(&indeg[d], 1);
}

__global__ __launch_bounds__(256) void k_scan1(const int* __restrict__ indeg,
                                               int* __restrict__ rowptr,
                                               int* __restrict__ bsum) {
    __shared__ int ws4[4];
    int t = threadIdx.x;
    int i = blockIdx.x * 256 + t;
    int v = (i < NN) ? indeg[i] : 0;
    int x = v;
#pragma unroll
    for (int d = 1; d < 64; d <<= 1) {
        int y = __shfl_up(x, d, 64);
        if ((t & 63) >= d) x += y;
    }
    if ((t & 63) == 63) ws4[t >> 6] = x;
    __syncthreads();
    if (t == 0) {
        int s = 0;
#pragma unroll
        for (int w = 0; w < 4; ++w) { int tmp = ws4[w]; ws4[w] = s; s += tmp; }
        bsum[blockIdx.x] = s;
    }
    __syncthreads();
    if (i < NN) rowptr[i] = x - v + ws4[t >> 6];
}

__global__ __launch_bounds__(512) void k_scan2(int* __restrict__ bsum, int nb) {
    __shared__ int ws8[8];
    int t = threadIdx.x;
    int v = (t < nb) ? bsum[t] : 0;
    int x = v;
#pragma unroll
    for (int d = 1; d < 64; d <<= 1) {
        int y = __shfl_up(x, d, 64);
        if ((t & 63) >= d) x += y;
    }
    if ((t & 63) == 63) ws8[t >> 6] = x;
    __syncthreads();
    if (t == 0) {
        int s = 0;
#pragma unroll
        for (int w = 0; w < 8; ++w) { int tmp = ws8[w]; ws8[w] = s; s += tmp; }
    }
    __syncthreads();
    if (t < nb) bsum[t] = x - v + ws8[t >> 6];
}

__global__ void k_scan3(int* __restrict__ rowptr, const int* __restrict__ bsum,
                        int* __restrict__ cursor) {
    int i = blockIdx.x * 256 + threadIdx.x;
    if (i < NN) {
        int r = rowptr[i] + bsum[blockIdx.x];
        rowptr[i] = r;
        cursor[i] = r;
    }
    if (i == 0) rowptr[NN] = NE;
}

__global__ void k_dinv_i(const int* __restrict__ indeg, float* __restrict__ dinv) {
    int i = blockIdx.x * blockDim.x + threadIdx.x;
    if (i < NN) dinv[i] = rsqrtf((float)indeg[i] + 1.0f);
}

// fill CSR with packed (src, weight)
__global__ void k_fill(const void* __restrict__ ei, const int* __restrict__ flags,
                       const float* __restrict__ dinv,
                       int* __restrict__ cursor, int2* __restrict__ csrp) {
    int e = blockIdx.x * blockDim.x + threadIdx.x;
    if (e >= NE) return;
    bool is64 = (flags[0] == 0);
    int s = (int)ld_idx(ei, e, is64);
    int d = (int)ld_idx(ei, (long long)NE + e, is64);
    int pos = atomicAdd(&cursor[d], 1);
    float w = dinv[s] * dinv[d];
    csrp[pos] = make_int2(s, __float_as_int(w));
}

// ---------------- bf16 conversion ----------------

__global__ void k_cvt_x(const float* __restrict__ x, u16* __restrict__ xb) {
    long long i = ((long long)blockIdx.x * blockDim.x + threadIdx.x) * 4;
    if (i >= (long long)NN * CH) return;
    float4 v = *(const float4*)(x + i);
    ushort4 o;
    o.x = f2bf(v.x); o.y = f2bf(v.y); o.z = f2bf(v.z); o.w = f2bf(v.w);
    *(ushort4*)(xb + i) = o;
}

// Wt[l][c][k] = bf16(Ws[l][k][c])
__global__ void k_cvt_w(const float* __restrict__ Ws, u16* __restrict__ Wt) {
    int i = blockIdx.x * blockDim.x + threadIdx.x;
    if (i >= NL * CH * CH) return;
    int l = i >> 14;
    int c = (i >> 7) & 127;
    int k = i & 127;
    Wt[i] = f2bf(Ws[(l << 14) + (k << 7) + c]);
}

// ---------------- MFMA GEMM: out[N,128] = A[N,128] @ W, all bf16 ----------------
__global__ __launch_bounds__(256) void k_mm(const u16* __restrict__ A,
                                            const u16* __restrict__ Wt,
                                            u16* __restrict__ out) {
    int tid = threadIdx.x;
    int lane = tid & 63;
    int wv = tid >> 6;
    int rbase = blockIdx.x * 128 + wv * 32;
    int lm = lane & 15;
    int lk = (lane >> 4) << 3;

    f4 acc[2][8];
#pragma unroll
    for (int m = 0; m < 2; ++m)
#pragma unroll
        for (int n = 0; n < 8; ++n) acc[m][n] = (f4){0.f, 0.f, 0.f, 0.f};

    int r0 = rbase + lm;      if (r0 >= NN) r0 = NN - 1;
    int r1 = rbase + 16 + lm; if (r1 >= NN) r1 = NN - 1;

#pragma unroll
    for (int kk = 0; kk < 4; ++kk) {
        int ko = kk * 32 + lk;
        bf8 a0 = *(const bf8*)(A + (size_t)r0 * CH + ko);
        bf8 a1 = *(const bf8*)(A + (size_t)r1 * CH + ko);
#pragma unroll
        for (int n = 0; n < 8; ++n) {
            bf8 b = *(const bf8*)(Wt + (n * 16 + lm) * CH + ko);
            acc[0][n] = __builtin_amdgcn_mfma_f32_16x16x32_bf16(a0, b, acc[0][n], 0, 0, 0);
            acc[1][n] = __builtin_amdgcn_mfma_f32_16x16x32_bf16(a1, b, acc[1][n], 0, 0, 0);
        }
    }

#pragma unroll
    for (int m = 0; m < 2; ++m) {
        int rb = rbase + m * 16 + (lane >> 4) * 4;
#pragma unroll
        for (int r = 0; r < 4; ++r) {
            int row = rb + r;
            if (row < NN) {
#pragma unroll
                for (int n = 0; n < 8; ++n)
                    out[(size_t)row * CH + n * 16 + lm] = f2bf(acc[m][n][r]);
            }
        }
    }
}

// ---------------- aggregation: gather + self + bias + relu ----------------
// If hw != nullptr (last layer): fuse head dot-product, write partial[node],
// skip the h store entirely.
__global__ __launch_bounds__(256) void k_aggr(const u16* __restrict__ t,
                                              const int* __restrict__ rowptr,
                                              const int2* __restrict__ csrp,
                                              const float* __restrict__ dinv,
                                              const float* __restrict__ b,
                                              u16* __restrict__ h,
                                              const float* __restrict__ hw,
                                              float* __restrict__ partial) {
    int node = (blockIdx.x << 2) + (threadIdx.x >> 6);
    if (node >= NN) return;
    int lane = threadIdx.x & 63;
    int c = lane << 1;
    int beg = rowptr[node], end = rowptr[node + 1];
    float dn = dinv[node];
    u32 sv = *(const u32*)(t + (size_t)node * CH + c);
    float sl = dn * dn;
    float a0 = bflo(sv) * sl, a1 = bfhi(sv) * sl;

    for (int base = beg; base < end; base += 64) {
        int2 pk = make_int2(0, 0);
        if (base + lane < end) pk = csrp[base + lane];
        int cnt = min(64, end - base);
        int j = 0;
        for (; j + 4 <= cnt; j += 4) {
            int s0 = __shfl(pk.x, j),     s1 = __shfl(pk.x, j + 1);
            int s2 = __shfl(pk.x, j + 2), s3 = __shfl(pk.x, j + 3);
            float w0 = __uint_as_float((u32)__shfl(pk.y, j));
            float w1 = __uint_as_float((u32)__shfl(pk.y, j + 1));
            float w2 = __uint_as_float((u32)__shfl(pk.y, j + 2));
            float w3 = __uint_as_float((u32)__shfl(pk.y, j + 3));
            u32 t0 = *(const u32*)(t + (size_t)s0 * CH + c);
            u32 t1 = *(const u32*)(t + (size_t)s1 * CH + c);
            u32 t2 = *(const u32*)(t + (size_t)s2 * CH + c);
            u32 t3 = *(const u32*)(t + (size_t)s3 * CH + c);
            a0 = fmaf(bflo(t0), w0, a0); a1 = fmaf(bfhi(t0), w0, a1);
            a0 = fmaf(bflo(t1), w1, a0); a1 = fmaf(bfhi(t1), w1, a1);
            a0 = fmaf(bflo(t2), w2, a0); a1 = fmaf(bfhi(t2), w2, a1);
            a0 = fmaf(bflo(t3), w3, a0); a1 = fmaf(bfhi(t3), w3, a1);
        }
        for (; j < cnt; ++j) {
            int s = __shfl(pk.x, j);
            float w = __uint_as_float((u32)__shfl(pk.y, j));
            u32 tv = *(const u32*)(t + (size_t)s * CH + c);
            a0 = fmaf(bflo(tv), w, a0); a1 = fmaf(bfhi(tv), w, a1);
        }
    }
    float2 bv = *(const float2*)(b + c);
    float r0 = fmaxf(a0 + bv.x, 0.f);
    float r1 = fmaxf(a1 + bv.y, 0.f);
    if (hw) {
        float2 wv = *(const float2*)(hw + c);
        float acc = r0 * wv.x + r1 * wv.y;
#pragma unroll
        for (int off = 32; off > 0; off >>= 1) acc += __shfl_down(acc, off);
        if (lane == 0) partial[node] = acc;
    } else {
        *(u32*)(h + (size_t)node * CH + c) = ((u32)f2bf(r1) << 16) | (u32)f2bf(r0);
    }
}

// ---------------- head: per-graph segmented sum over sorted batch ----------------

__device__ __forceinline__ int lbound(const void* bt, bool is64, int target) {
    int lo = 0, hi = NN;
    while (lo < hi) {
        int mid = (lo + hi) >> 1;
        long long v = ld_idx(bt, mid, is64);
        if (v < (long long)target) lo = mid + 1; else hi = mid;
    }
    return lo;
}

__global__ __launch_bounds__(256) void k_head(const float* __restrict__ partial,
                                              const void* __restrict__ batch,
                                              const int* __restrict__ flags,
                                              const float* __restrict__ hb,
                                              float* __restrict__ out) {
    int g = blockIdx.x * 4 + (threadIdx.x >> 6);
    if (g >= NG) return;
    int lane = threadIdx.x & 63;
    bool is64 = (flags[1] == 0);
    int lo = lbound(batch, is64, g);
    int hi = lbound(batch, is64, g + 1);
    float s = 0.f;
    for (int i = lo + lane; i < hi; i += 64) s += partial[i];
#pragma unroll
    for (int off = 32; off > 0; off >>= 1) s += __shfl_down(s, off);
    if (lane == 0) out[g] = s + hb[0];
}

extern "C" void kernel_launch(void* const* d_in, const int* in_sizes, int n_in,
                              void* d_out, int out_size, void* d_ws, size_t ws_size,
                              hipStream_t stream) {
    const float* x  = (const float*)d_in[0];
    const void*  ei = d_in[1];
    const void*  bt = d_in[2];
    const float* Ws = (const float*)d_in[3];
    const float* bs = (const float*)d_in[4];
    const float* hw = (const float*)d_in[5];
    const float* hb = (const float*)d_in[6];
    float* out = (float*)d_out;

    char* ws = (char*)d_ws;
    size_t p = 0;
    auto alloc = [&](size_t bytes) { size_t r = p; p += (bytes + 255) & ~(size_t)255; return r; };
    size_t o_flags  = alloc(256);
    size_t o_dinv   = alloc((size_t)NN * 4);
    size_t o_indeg  = alloc((size_t)NN * 4);
    size_t o_rowptr = alloc((size_t)(NN + 1) * 4);
    size_t o_cursor = alloc((size_t)NN * 4);
    size_t o_bsum   = alloc(512 * 4);
    size_t o_part   = alloc((size_t)NN * 4);
    size_t o_csrp   = alloc((size_t)NE * 8);
    size_t o_xb     = alloc((size_t)NN * CH * 2);
    size_t o_tb     = alloc((size_t)NN * CH * 2);
    size_t o_hb     = alloc((size_t)NN * CH * 2);
    size_t o_wt     = alloc((size_t)NL * CH * CH * 2);
    (void)ws_size;  // ~67 MB, fits (R2 used ~111 MB)

    int*   flags  = (int*)(ws + o_flags);
    float* dinv   = (float*)(ws + o_dinv);
    int*   indeg  = (int*)(ws + o_indeg);
    int*   rowptr = (int*)(ws + o_rowptr);
    int*   cursor = (int*)(ws + o_cursor);
    int*   bsum   = (int*)(ws + o_bsum);
    float* part   = (float*)(ws + o_part);
    int2*  csrp   = (int2*)(ws + o_csrp);
    u16*   xb     = (u16*)(ws + o_xb);
    u16*   tb     = (u16*)(ws + o_tb);
    u16*   hbuf   = (u16*)(ws + o_hb);
    u16*   Wt     = (u16*)(ws + o_wt);

    const int nb = (NN + 255) / 256;   // 391

    k_zero_flags<<<1, 64, 0, stream>>>(flags);
    k_detect<<<256, 256, 0, stream>>>((const int*)ei, (const int*)bt, flags);

    k_zeroi<<<nb, 256, 0, stream>>>(indeg, NN);
    k_count<<<(NE + 255) / 256, 256, 0, stream>>>(ei, flags, indeg);
    k_scan1<<<nb, 256, 0, stream>>>(indeg, rowptr, bsum);
    k_scan2<<<1, 512, 0, stream>>>(bsum, nb);
    k_scan3<<<nb, 256, 0, stream>>>(rowptr, bsum, cursor);
    k_dinv_i<<<nb, 256, 0, stream>>>(indeg, dinv);
    k_fill<<<(NE + 255) / 256, 256, 0, stream>>>(ei, flags, dinv, cursor, csrp);

    k_cvt_x<<<(int)(((long long)NN * CH / 4 + 255) / 256), 256, 0, stream>>>(x, xb);
    k_cvt_w<<<(NL * CH * CH + 255) / 256, 256, 0, stream>>>(Ws, Wt);

    const u16* hin = xb;
    for (int l = 0; l < NL; ++l) {
        bool last = (l == NL - 1);
        k_mm<<<(NN + 127) / 128, 256, 0, stream>>>(hin, Wt + (size_t)l * CH * CH, tb);
        k_aggr<<<(NN + 3) / 4, 256, 0, stream>>>(tb, rowptr, csrp, dinv,
                                                 bs + (size_t)l * CH, hbuf,
                                                 last ? hw : nullptr, part);
        hin = hbuf;
    }

    k_head<<<(NG + 3) / 4, 256, 0, stream>>>(part, bt, flags, hb, out);
}

// Round 5
// 490.016 us; speedup vs baseline: 18.3085x; 1.0041x over previous
//
#include <hip/hip_runtime.h>

#define NN 100000
#define NE 1600000
#define CH 128
#define NG 512
#define NL 3

typedef short bf8 __attribute__((ext_vector_type(8)));
typedef float f4 __attribute__((ext_vector_type(4)));
typedef unsigned int u32x4 __attribute__((ext_vector_type(4)));
typedef unsigned short u16;
typedef unsigned int u32;

__device__ __forceinline__ long long ld_idx(const void* p, long long i, bool is64) {
    return is64 ? ((const long long*)p)[i] : (long long)((const int*)p)[i];
}
__device__ __forceinline__ u16 f2bf(float f) {
    u32 u = __float_as_uint(f);
    u += 0x7fffu + ((u >> 16) & 1u);
    return (u16)(u >> 16);
}
__device__ __forceinline__ float bflo(u32 v) { return __uint_as_float(v << 16); }
__device__ __forceinline__ float bfhi(u32 v) { return __uint_as_float(v & 0xffff0000u); }

// zero indeg + flags (merged)
__global__ void k_zeroi(int* p, int n, int* flags) {
    int i = blockIdx.x * blockDim.x + threadIdx.x;
    if (i < n) p[i] = 0;
    if (blockIdx.x == 0 && threadIdx.x < 2) flags[threadIdx.x] = 0;
}

// Detect int64 vs int32 index arrays: for int64 values < 2^31, every odd
// 32-bit word (within the first n_elem words, present either way) is zero.
__global__ void k_detect(const int* __restrict__ ei32, const int* __restrict__ b32, int* flags) {
    int acc_e = 0, acc_b = 0;
    long long stride = (long long)gridDim.x * blockDim.x;
    long long t0 = (long long)blockIdx.x * blockDim.x + threadIdx.x;
    for (long long i = t0; i < NE; i += stride) acc_e |= ei32[2 * i + 1];
    for (long long i = t0; i < NN / 2; i += stride) acc_b |= b32[2 * i + 1];
    if (acc_e) atomicOr(&flags[0], 1);
    if (acc_b) atomicOr(&flags[1], 1);
}

// ---------------- CSR build ----------------

__global__ void k_count(const void* __restrict__ ei, const int* __restrict__ flags,
                        int* __restrict__ indeg) {
    int e = blockIdx.x * blockDim.x + threadIdx.x;
    if (e >= NE) return;
    bool is64 = (flags[0] == 0);
    int d = (int)ld_idx(ei, (long long)NE + e, is64);
    atomicAdd(&indeg[d], 1);
}

__global__ __launch_bounds__(256) void k_scan1(const int* __restrict__ indeg,
                                               int* __restrict__ rowptr,
                                               int* __restrict__ bsum) {
    __shared__ int ws4[4];
    int t = threadIdx.x;
    int i = blockIdx.x * 256 + t;
    int v = (i < NN) ? indeg[i] : 0;
    int x = v;
#pragma unroll
    for (int d = 1; d < 64; d <<= 1) {
        int y = __shfl_up(x, d, 64);
        if ((t & 63) >= d) x += y;
    }
    if ((t & 63) == 63) ws4[t >> 6] = x;
    __syncthreads();
    if (t == 0) {
        int s = 0;
#pragma unroll
        for (int w = 0; w < 4; ++w) { int tmp = ws4[w]; ws4[w] = s; s += tmp; }
        bsum[blockIdx.x] = s;
    }
    __syncthreads();
    if (i < NN) rowptr[i] = x - v + ws4[t >> 6];
}

__global__ __launch_bounds__(512) void k_scan2(int* __restrict__ bsum, int nb) {
    __shared__ int ws8[8];
    int t = threadIdx.x;
    int v = (t < nb) ? bsum[t] : 0;
    int x = v;
#pragma unroll
    for (int d = 1; d < 64; d <<= 1) {
        int y = __shfl_up(x, d, 64);
        if ((t & 63) >= d) x += y;
    }
    if ((t & 63) == 63) ws8[t >> 6] = x;
    __syncthreads();
    if (t == 0) {
        int s = 0;
#pragma unroll
        for (int w = 0; w < 8; ++w) { int tmp = ws8[w]; ws8[w] = s; s += tmp; }
    }
    __syncthreads();
    if (t < nb) bsum[t] = x - v + ws8[t >> 6];
}

__global__ void k_scan3(int* __restrict__ rowptr, const int* __restrict__ bsum,
                        int* __restrict__ cursor) {
    int i = blockIdx.x * 256 + threadIdx.x;
    if (i < NN) {
        int r = rowptr[i] + bsum[blockIdx.x];
        rowptr[i] = r;
        cursor[i] = r;
    }
    if (i == 0) rowptr[NN] = NE;
}

__global__ void k_dinv_i(const int* __restrict__ indeg, float* __restrict__ dinv) {
    int i = blockIdx.x * blockDim.x + threadIdx.x;
    if (i < NN) dinv[i] = rsqrtf((float)indeg[i] + 1.0f);
}

// fill CSR with packed (src, weight)
__global__ void k_fill(const void* __restrict__ ei, const int* __restrict__ flags,
                       const float* __restrict__ dinv,
                       int* __restrict__ cursor, int2* __restrict__ csrp) {
    int e = blockIdx.x * blockDim.x + threadIdx.x;
    if (e >= NE) return;
    bool is64 = (flags[0] == 0);
    int s = (int)ld_idx(ei, e, is64);
    int d = (int)ld_idx(ei, (long long)NE + e, is64);
    int pos = atomicAdd(&cursor[d], 1);
    float w = dinv[s] * dinv[d];
    csrp[pos] = make_int2(s, __float_as_int(w));
}

// ---------------- bf16 conversion ----------------

__global__ void k_cvt_x(const float* __restrict__ x, u16* __restrict__ xb) {
    long long i = ((long long)blockIdx.x * blockDim.x + threadIdx.x) * 4;
    if (i >= (long long)NN * CH) return;
    float4 v = *(const float4*)(x + i);
    ushort4 o;
    o.x = f2bf(v.x); o.y = f2bf(v.y); o.z = f2bf(v.z); o.w = f2bf(v.w);
    *(ushort4*)(xb + i) = o;
}

// Wt[l][c][k] = bf16(Ws[l][k][c])
__global__ void k_cvt_w(const float* __restrict__ Ws, u16* __restrict__ Wt) {
    int i = blockIdx.x * blockDim.x + threadIdx.x;
    if (i >= NL * CH * CH) return;
    int l = i >> 14;
    int c = (i >> 7) & 127;
    int k = i & 127;
    Wt[i] = f2bf(Ws[(l << 14) + (k << 7) + c]);
}

// ---------------- MFMA GEMM: out[N,128] = A[N,128] @ W, all bf16 ----------------
__global__ __launch_bounds__(256) void k_mm(const u16* __restrict__ A,
                                            const u16* __restrict__ Wt,
                                            u16* __restrict__ out) {
    int tid = threadIdx.x;
    int lane = tid & 63;
    int wv = tid >> 6;
    int rbase = blockIdx.x * 128 + wv * 32;
    int lm = lane & 15;
    int lk = (lane >> 4) << 3;

    f4 acc[2][8];
#pragma unroll
    for (int m = 0; m < 2; ++m)
#pragma unroll
        for (int n = 0; n < 8; ++n) acc[m][n] = (f4){0.f, 0.f, 0.f, 0.f};

    int r0 = rbase + lm;      if (r0 >= NN) r0 = NN - 1;
    int r1 = rbase + 16 + lm; if (r1 >= NN) r1 = NN - 1;

#pragma unroll
    for (int kk = 0; kk < 4; ++kk) {
        int ko = kk * 32 + lk;
        bf8 a0 = *(const bf8*)(A + (size_t)r0 * CH + ko);
        bf8 a1 = *(const bf8*)(A + (size_t)r1 * CH + ko);
#pragma unroll
        for (int n = 0; n < 8; ++n) {
            bf8 b = *(const bf8*)(Wt + (n * 16 + lm) * CH + ko);
            acc[0][n] = __builtin_amdgcn_mfma_f32_16x16x32_bf16(a0, b, acc[0][n], 0, 0, 0);
            acc[1][n] = __builtin_amdgcn_mfma_f32_16x16x32_bf16(a1, b, acc[1][n], 0, 0, 0);
        }
    }

#pragma unroll
    for (int m = 0; m < 2; ++m) {
        int rb = rbase + m * 16 + (lane >> 4) * 4;
#pragma unroll
        for (int r = 0; r < 4; ++r) {
            int row = rb + r;
            if (row < NN) {
#pragma unroll
                for (int n = 0; n < 8; ++n)
                    out[(size_t)row * CH + n * 16 + lm] = f2bf(acc[m][n][r]);
            }
        }
    }
}

// ---------------- aggregation v2: 16 lanes/edge, 16B loads ----------------
// 4 groups of 16 lanes; group g handles edges j0+g; lane holds 8 channels.
// If hw != nullptr (last layer): fuse head dot-product, write partial[node].
__global__ __launch_bounds__(256) void k_aggr(const u16* __restrict__ t,
                                              const int* __restrict__ rowptr,
                                              const int2* __restrict__ csrp,
                                              const float* __restrict__ dinv,
                                              const float* __restrict__ b,
                                              u16* __restrict__ h,
                                              const float* __restrict__ hw,
                                              float* __restrict__ partial) {
    int node = (blockIdx.x << 2) + (threadIdx.x >> 6);
    if (node >= NN) return;
    int lane = threadIdx.x & 63;
    int g = lane >> 4;
    int l16 = lane & 15;
    int c8 = l16 << 3;                    // channel base (8 ch/lane)
    const u32x4* tp = (const u32x4*)t;    // row = 16 u32x4

    int beg = rowptr[node], end = rowptr[node + 1];
    float acc[8];
#pragma unroll
    for (int k = 0; k < 8; ++k) acc[k] = 0.f;

    for (int base = beg; base < end; base += 64) {
        int2 pk = make_int2(0, 0);
        if (base + lane < end) pk = csrp[base + lane];
        int cnt = min(64, end - base);
        for (int j0 = 0; j0 < cnt; j0 += 4) {
            int src = __shfl(pk.x, j0 + g);
            float w = __uint_as_float((u32)__shfl(pk.y, j0 + g));
            u32x4 v = tp[src * 16 + l16];
            acc[0] = fmaf(bflo(v[0]), w, acc[0]); acc[1] = fmaf(bfhi(v[0]), w, acc[1]);
            acc[2] = fmaf(bflo(v[1]), w, acc[2]); acc[3] = fmaf(bfhi(v[1]), w, acc[3]);
            acc[4] = fmaf(bflo(v[2]), w, acc[4]); acc[5] = fmaf(bfhi(v[2]), w, acc[5]);
            acc[6] = fmaf(bflo(v[3]), w, acc[6]); acc[7] = fmaf(bfhi(v[3]), w, acc[7]);
        }
    }
    // cross-group reduction: lanes {l16, l16+16, l16+32, l16+48} -> total in all
#pragma unroll
    for (int k = 0; k < 8; ++k) {
        acc[k] += __shfl_xor(acc[k], 16);
        acc[k] += __shfl_xor(acc[k], 32);
    }
    // self-loop + bias + relu
    float dn = dinv[node];
    float sl = dn * dn;
    u32x4 sv = tp[node * 16 + l16];
    float r[8];
    r[0] = fmaf(bflo(sv[0]), sl, acc[0]); r[1] = fmaf(bfhi(sv[0]), sl, acc[1]);
    r[2] = fmaf(bflo(sv[1]), sl, acc[2]); r[3] = fmaf(bfhi(sv[1]), sl, acc[3]);
    r[4] = fmaf(bflo(sv[2]), sl, acc[4]); r[5] = fmaf(bfhi(sv[2]), sl, acc[5]);
    r[6] = fmaf(bflo(sv[3]), sl, acc[6]); r[7] = fmaf(bfhi(sv[3]), sl, acc[7]);
    float4 b0 = *(const float4*)(b + c8);
    float4 b1 = *(const float4*)(b + c8 + 4);
    r[0] = fmaxf(r[0] + b0.x, 0.f); r[1] = fmaxf(r[1] + b0.y, 0.f);
    r[2] = fmaxf(r[2] + b0.z, 0.f); r[3] = fmaxf(r[3] + b0.w, 0.f);
    r[4] = fmaxf(r[4] + b1.x, 0.f); r[5] = fmaxf(r[5] + b1.y, 0.f);
    r[6] = fmaxf(r[6] + b1.z, 0.f); r[7] = fmaxf(r[7] + b1.w, 0.f);

    if (hw) {
        float4 w0 = *(const float4*)(hw + c8);
        float4 w1 = *(const float4*)(hw + c8 + 4);
        float d = r[0] * w0.x + r[1] * w0.y + r[2] * w0.z + r[3] * w0.w
                + r[4] * w1.x + r[5] * w1.y + r[6] * w1.z + r[7] * w1.w;
#pragma unroll
        for (int off = 8; off > 0; off >>= 1) d += __shfl_xor(d, off);
        if (lane == 0) partial[node] = d;
    } else if (g == 0) {
        u32x4 o;
        o[0] = ((u32)f2bf(r[1]) << 16) | (u32)f2bf(r[0]);
        o[1] = ((u32)f2bf(r[3]) << 16) | (u32)f2bf(r[2]);
        o[2] = ((u32)f2bf(r[5]) << 16) | (u32)f2bf(r[4]);
        o[3] = ((u32)f2bf(r[7]) << 16) | (u32)f2bf(r[6]);
        ((u32x4*)h)[node * 16 + l16] = o;
    }
}

// ---------------- head: per-graph segmented sum over sorted batch ----------------

__device__ __forceinline__ int lbound(const void* bt, bool is64, int target) {
    int lo = 0, hi = NN;
    while (lo < hi) {
        int mid = (lo + hi) >> 1;
        long long v = ld_idx(bt, mid, is64);
        if (v < (long long)target) lo = mid + 1; else hi = mid;
    }
    return lo;
}

__global__ __launch_bounds__(256) void k_head(const float* __restrict__ partial,
                                              const void* __restrict__ batch,
                                              const int* __restrict__ flags,
                                              const float* __restrict__ hb,
                                              float* __restrict__ out) {
    int g = blockIdx.x * 4 + (threadIdx.x >> 6);
    if (g >= NG) return;
    int lane = threadIdx.x & 63;
    bool is64 = (flags[1] == 0);
    int lo = lbound(batch, is64, g);
    int hi = lbound(batch, is64, g + 1);
    float s = 0.f;
    for (int i = lo + lane; i < hi; i += 64) s += partial[i];
#pragma unroll
    for (int off = 32; off > 0; off >>= 1) s += __shfl_down(s, off);
    if (lane == 0) out[g] = s + hb[0];
}

extern "C" void kernel_launch(void* const* d_in, const int* in_sizes, int n_in,
                              void* d_out, int out_size, void* d_ws, size_t ws_size,
                              hipStream_t stream) {
    const float* x  = (const float*)d_in[0];
    const void*  ei = d_in[1];
    const void*  bt = d_in[2];
    const float* Ws = (const float*)d_in[3];
    const float* bs = (const float*)d_in[4];
    const float* hw = (const float*)d_in[5];
    const float* hb = (const float*)d_in[6];
    float* out = (float*)d_out;

    char* ws = (char*)d_ws;
    size_t p = 0;
    auto alloc = [&](size_t bytes) { size_t r = p; p += (bytes + 255) & ~(size_t)255; return r; };
    size_t o_flags  = alloc(256);
    size_t o_dinv   = alloc((size_t)NN * 4);
    size_t o_indeg  = alloc((size_t)NN * 4);
    size_t o_rowptr = alloc((size_t)(NN + 1) * 4);
    size_t o_cursor = alloc((size_t)NN * 4);
    size_t o_bsum   = alloc(512 * 4);
    size_t o_part   = alloc((size_t)NN * 4);
    size_t o_csrp   = alloc((size_t)NE * 8);
    size_t o_xb     = alloc((size_t)NN * CH * 2);
    size_t o_tb     = alloc((size_t)NN * CH * 2);
    size_t o_hb     = alloc((size_t)NN * CH * 2);
    size_t o_wt     = alloc((size_t)NL * CH * CH * 2);
    (void)ws_size;  // ~67 MB

    int*   flags  = (int*)(ws + o_flags);
    float* dinv   = (float*)(ws + o_dinv);
    int*   indeg  = (int*)(ws + o_indeg);
    int*   rowptr = (int*)(ws + o_rowptr);
    int*   cursor = (int*)(ws + o_cursor);
    int*   bsum   = (int*)(ws + o_bsum);
    float* part   = (float*)(ws + o_part);
    int2*  csrp   = (int2*)(ws + o_csrp);
    u16*   xb     = (u16*)(ws + o_xb);
    u16*   tb     = (u16*)(ws + o_tb);
    u16*   hbuf   = (u16*)(ws + o_hb);
    u16*   Wt     = (u16*)(ws + o_wt);

    const int nb = (NN + 255) / 256;   // 391

    k_zeroi<<<nb, 256, 0, stream>>>(indeg, NN, flags);
    k_detect<<<256, 256, 0, stream>>>((const int*)ei, (const int*)bt, flags);
    k_count<<<(NE + 255) / 256, 256, 0, stream>>>(ei, flags, indeg);
    k_scan1<<<nb, 256, 0, stream>>>(indeg, rowptr, bsum);
    k_scan2<<<1, 512, 0, stream>>>(bsum, nb);
    k_scan3<<<nb, 256, 0, stream>>>(rowptr, bsum, cursor);
    k_dinv_i<<<nb, 256, 0, stream>>>(indeg, dinv);
    k_fill<<<(NE + 255) / 256, 256, 0, stream>>>(ei, flags, dinv, cursor, csrp);

    k_cvt_x<<<(int)(((long long)NN * CH / 4 + 255) / 256), 256, 0, stream>>>(x, xb);
    k_cvt_w<<<(NL * CH * CH + 255) / 256, 256, 0, stream>>>(Ws, Wt);

    const u16* hin = xb;
    for (int l = 0; l < NL; ++l) {
        bool last = (l == NL - 1);
        k_mm<<<(NN + 127) / 128, 256, 0, stream>>>(hin, Wt + (size_t)l * CH * CH, tb);
        k_aggr<<<(NN + 3) / 4, 256, 0, stream>>>(tb, rowptr, csrp, dinv,
                                                 bs + (size_t)l * CH, hbuf,
                                                 last ? hw : nullptr, part);
        hin = hbuf;
    }

    k_head<<<(NG + 3) / 4, 256, 0, stream>>>(part, bt, flags, hb, out);
}

// Round 6
// 448.494 us; speedup vs baseline: 20.0035x; 1.0926x over previous
//
#include <hip/hip_runtime.h>

#define NN 100000
#define NE 1600000
#define CH 128
#define NG 512
#define NL 3
#define BSZ 512                      // nodes per bucket
#define NBUK ((NN + BSZ - 1) / BSZ)  // 196
#define TILE 4096                    // edges per k_bin block

typedef short bf8 __attribute__((ext_vector_type(8)));
typedef float f4 __attribute__((ext_vector_type(4)));
typedef unsigned int u32x4 __attribute__((ext_vector_type(4)));
typedef unsigned short u16;
typedef unsigned int u32;

__device__ __forceinline__ long long ld_idx(const void* p, long long i, bool is64) {
    return is64 ? ((const long long*)p)[i] : (long long)((const int*)p)[i];
}
__device__ __forceinline__ u16 f2bf(float f) {
    u32 u = __float_as_uint(f);
    u += 0x7fffu + ((u >> 16) & 1u);
    return (u16)(u >> 16);
}
__device__ __forceinline__ float bflo(u32 v) { return __uint_as_float(v << 16); }
__device__ __forceinline__ float bfhi(u32 v) { return __uint_as_float(v & 0xffff0000u); }

// zero indeg + flags (merged)
__global__ void k_zeroi(int* p, int n, int* flags) {
    int i = blockIdx.x * blockDim.x + threadIdx.x;
    if (i < n) p[i] = 0;
    if (blockIdx.x == 0 && threadIdx.x < 2) flags[threadIdx.x] = 0;
}

// Detect int64 vs int32 index arrays: for int64 values < 2^31, every odd
// 32-bit word (within the first n_elem words, present either way) is zero.
__global__ void k_detect(const int* __restrict__ ei32, const int* __restrict__ b32, int* flags) {
    int acc_e = 0, acc_b = 0;
    long long stride = (long long)gridDim.x * blockDim.x;
    long long t0 = (long long)blockIdx.x * blockDim.x + threadIdx.x;
    for (long long i = t0; i < NE; i += stride) acc_e |= ei32[2 * i + 1];
    for (long long i = t0; i < NN / 2; i += stride) acc_b |= b32[2 * i + 1];
    if (acc_e) atomicOr(&flags[0], 1);
    if (acc_b) atomicOr(&flags[1], 1);
}

// ---------------- CSR build ----------------

__global__ void k_count(const void* __restrict__ ei, const int* __restrict__ flags,
                        int* __restrict__ indeg) {
    int e = blockIdx.x * blockDim.x + threadIdx.x;
    if (e >= NE) return;
    bool is64 = (flags[0] == 0);
    int d = (int)ld_idx(ei, (long long)NE + e, is64);
    atomicAdd(&indeg[d], 1);
}

__global__ __launch_bounds__(256) void k_scan1(const int* __restrict__ indeg,
                                               int* __restrict__ rowptr,
                                               int* __restrict__ bsum) {
    __shared__ int ws4[4];
    int t = threadIdx.x;
    int i = blockIdx.x * 256 + t;
    int v = (i < NN) ? indeg[i] : 0;
    int x = v;
#pragma unroll
    for (int d = 1; d < 64; d <<= 1) {
        int y = __shfl_up(x, d, 64);
        if ((t & 63) >= d) x += y;
    }
    if ((t & 63) == 63) ws4[t >> 6] = x;
    __syncthreads();
    if (t == 0) {
        int s = 0;
#pragma unroll
        for (int w = 0; w < 4; ++w) { int tmp = ws4[w]; ws4[w] = s; s += tmp; }
        bsum[blockIdx.x] = s;
    }
    __syncthreads();
    if (i < NN) rowptr[i] = x - v + ws4[t >> 6];
}

__global__ __launch_bounds__(512) void k_scan2(int* __restrict__ bsum, int nb) {
    __shared__ int ws8[8];
    int t = threadIdx.x;
    int v = (t < nb) ? bsum[t] : 0;
    int x = v;
#pragma unroll
    for (int d = 1; d < 64; d <<= 1) {
        int y = __shfl_up(x, d, 64);
        if ((t & 63) >= d) x += y;
    }
    if ((t & 63) == 63) ws8[t >> 6] = x;
    __syncthreads();
    if (t == 0) {
        int s = 0;
#pragma unroll
        for (int w = 0; w < 8; ++w) { int tmp = ws8[w]; ws8[w] = s; s += tmp; }
    }
    __syncthreads();
    if (t < nb) bsum[t] = x - v + ws8[t >> 6];
}

// finalize rowptr; init per-bucket global cursors
__global__ void k_scan3(int* __restrict__ rowptr, const int* __restrict__ bsum,
                        int* __restrict__ gcur) {
    int i = blockIdx.x * 256 + threadIdx.x;
    if (i < NN) {
        int r = rowptr[i] + bsum[blockIdx.x];
        rowptr[i] = r;
        if ((i & (BSZ - 1)) == 0) gcur[i / BSZ] = r;
    }
    if (i == 0) rowptr[NN] = NE;
}

__global__ void k_dinv_i(const int* __restrict__ indeg, float* __restrict__ dinv) {
    int i = blockIdx.x * blockDim.x + threadIdx.x;
    if (i < NN) dinv[i] = rsqrtf((float)indeg[i] + 1.0f);
}

// ---- pass 1: bin edges by dst bucket, LDS-staged coalesced flush ----
__global__ __launch_bounds__(256) void k_bin(const void* __restrict__ ei,
                                             const int* __restrict__ flags,
                                             int* __restrict__ gcur,
                                             u32* __restrict__ bin) {
    __shared__ u32 stag[TILE];
    __shared__ int cnt[NBUK], loff[NBUK], lcur[NBUK], gb_s[NBUK];
    int tid = threadIdx.x;
    long long e0 = (long long)blockIdx.x * TILE;
    bool is64 = (flags[0] == 0);

    u32 rec[16];
    int bk[16];
#pragma unroll
    for (int k = 0; k < 16; ++k) {
        long long e = e0 + tid + k * 256;
        if (e < NE) {
            int s = (int)ld_idx(ei, e, is64);
            int d = (int)ld_idx(ei, NE + e, is64);
            rec[k] = ((u32)s << 9) | (u32)(d & (BSZ - 1));
            bk[k] = d >> 9;
        } else bk[k] = -1;
    }
    for (int b = tid; b < NBUK; b += 256) { cnt[b] = 0; lcur[b] = 0; }
    __syncthreads();
#pragma unroll
    for (int k = 0; k < 16; ++k)
        if (bk[k] >= 0) atomicAdd(&cnt[bk[k]], 1);
    __syncthreads();
    if (tid == 0) {
        int run = 0;
        for (int b = 0; b < NBUK; ++b) { loff[b] = run; run += cnt[b]; }
    }
    __syncthreads();
    if (tid < NBUK && cnt[tid] > 0) gb_s[tid] = atomicAdd(&gcur[tid], cnt[tid]);
    __syncthreads();
#pragma unroll
    for (int k = 0; k < 16; ++k)
        if (bk[k] >= 0) {
            int pos = loff[bk[k]] + atomicAdd(&lcur[bk[k]], 1);
            stag[pos] = rec[k];
        }
    __syncthreads();
    int wv = tid >> 6, lane = tid & 63;
    for (int b = wv; b < NBUK; b += 4) {
        int n = cnt[b];
        int gb = (n > 0) ? gb_s[b] : 0;
        int lo = loff[b];
        for (int j = lane; j < n; j += 64) bin[gb + j] = stag[lo + j];
    }
}

// ---- pass 2: within each bucket, place records at exact CSR slots ----
__global__ __launch_bounds__(512) void k_fillb(const u32* __restrict__ bin,
                                               const int* __restrict__ rowptr,
                                               u32* __restrict__ csr) {
    __shared__ int lcur[BSZ];
    int b = blockIdx.x;
    int tid = threadIdx.x;
    int nb0 = b * BSZ;
    int node = nb0 + tid;
    lcur[tid] = (node < NN) ? rowptr[node] : 0;
    int gb = rowptr[nb0];
    int ge = rowptr[min(nb0 + BSZ, NN)];
    __syncthreads();
    for (int i = gb + tid; i < ge; i += BSZ) {
        u32 rec = bin[i];
        int n = rec & (BSZ - 1);
        int pos = atomicAdd(&lcur[n], 1);
        csr[pos] = rec >> 9;
    }
}

// ---------------- bf16 conversion ----------------

__global__ void k_cvt_x(const float* __restrict__ x, u16* __restrict__ xb) {
    long long i = ((long long)blockIdx.x * blockDim.x + threadIdx.x) * 4;
    if (i >= (long long)NN * CH) return;
    float4 v = *(const float4*)(x + i);
    ushort4 o;
    o.x = f2bf(v.x); o.y = f2bf(v.y); o.z = f2bf(v.z); o.w = f2bf(v.w);
    *(ushort4*)(xb + i) = o;
}

// Wt[l][c][k] = bf16(Ws[l][k][c])
__global__ void k_cvt_w(const float* __restrict__ Ws, u16* __restrict__ Wt) {
    int i = blockIdx.x * blockDim.x + threadIdx.x;
    if (i >= NL * CH * CH) return;
    int l = i >> 14;
    int c = (i >> 7) & 127;
    int k = i & 127;
    Wt[i] = f2bf(Ws[(l << 14) + (k << 7) + c]);
}

// ---------------- MFMA GEMM: out[N,128] = A[N,128] @ W, all bf16 ----------------
__global__ __launch_bounds__(256) void k_mm(const u16* __restrict__ A,
                                            const u16* __restrict__ Wt,
                                            u16* __restrict__ out) {
    int tid = threadIdx.x;
    int lane = tid & 63;
    int wv = tid >> 6;
    int rbase = blockIdx.x * 128 + wv * 32;
    int lm = lane & 15;
    int lk = (lane >> 4) << 3;

    f4 acc[2][8];
#pragma unroll
    for (int m = 0; m < 2; ++m)
#pragma unroll
        for (int n = 0; n < 8; ++n) acc[m][n] = (f4){0.f, 0.f, 0.f, 0.f};

    int r0 = rbase + lm;      if (r0 >= NN) r0 = NN - 1;
    int r1 = rbase + 16 + lm; if (r1 >= NN) r1 = NN - 1;

#pragma unroll
    for (int kk = 0; kk < 4; ++kk) {
        int ko = kk * 32 + lk;
        bf8 a0 = *(const bf8*)(A + (size_t)r0 * CH + ko);
        bf8 a1 = *(const bf8*)(A + (size_t)r1 * CH + ko);
#pragma unroll
        for (int n = 0; n < 8; ++n) {
            bf8 b = *(const bf8*)(Wt + (n * 16 + lm) * CH + ko);
            acc[0][n] = __builtin_amdgcn_mfma_f32_16x16x32_bf16(a0, b, acc[0][n], 0, 0, 0);
            acc[1][n] = __builtin_amdgcn_mfma_f32_16x16x32_bf16(a1, b, acc[1][n], 0, 0, 0);
        }
    }

#pragma unroll
    for (int m = 0; m < 2; ++m) {
        int rb = rbase + m * 16 + (lane >> 4) * 4;
#pragma unroll
        for (int r = 0; r < 4; ++r) {
            int row = rb + r;
            if (row < NN) {
#pragma unroll
                for (int n = 0; n < 8; ++n)
                    out[(size_t)row * CH + n * 16 + lm] = f2bf(acc[m][n][r]);
            }
        }
    }
}

// ---------------- aggregation: 16 lanes/edge, 16B loads, src-only CSR ----------------
__global__ __launch_bounds__(256) void k_aggr(const u16* __restrict__ t,
                                              const int* __restrict__ rowptr,
                                              const u32* __restrict__ csr,
                                              const float* __restrict__ dinv,
                                              const float* __restrict__ b,
                                              u16* __restrict__ h,
                                              const float* __restrict__ hw,
                                              float* __restrict__ partial) {
    int node = (blockIdx.x << 2) + (threadIdx.x >> 6);
    if (node >= NN) return;
    int lane = threadIdx.x & 63;
    int g = lane >> 4;
    int l16 = lane & 15;
    int c8 = l16 << 3;
    const u32x4* tp = (const u32x4*)t;

    int beg = rowptr[node], end = rowptr[node + 1];
    float dn = dinv[node];
    float acc[8];
#pragma unroll
    for (int k = 0; k < 8; ++k) acc[k] = 0.f;

    for (int base = beg; base < end; base += 64) {
        int srcv = 0;
        float wl = 0.f;
        if (base + lane < end) {
            srcv = (int)csr[base + lane];
            wl = dinv[srcv] * dn;
        }
        int cnt = min(64, end - base);
        for (int j0 = 0; j0 < cnt; j0 += 4) {
            int src = __shfl(srcv, j0 + g);
            float w = __shfl(wl, j0 + g);
            u32x4 v = tp[src * 16 + l16];
            acc[0] = fmaf(bflo(v[0]), w, acc[0]); acc[1] = fmaf(bfhi(v[0]), w, acc[1]);
            acc[2] = fmaf(bflo(v[1]), w, acc[2]); acc[3] = fmaf(bfhi(v[1]), w, acc[3]);
            acc[4] = fmaf(bflo(v[2]), w, acc[4]); acc[5] = fmaf(bfhi(v[2]), w, acc[5]);
            acc[6] = fmaf(bflo(v[3]), w, acc[6]); acc[7] = fmaf(bfhi(v[3]), w, acc[7]);
        }
    }
#pragma unroll
    for (int k = 0; k < 8; ++k) {
        acc[k] += __shfl_xor(acc[k], 16);
        acc[k] += __shfl_xor(acc[k], 32);
    }
    float sl = dn * dn;
    u32x4 sv = tp[node * 16 + l16];
    float r[8];
    r[0] = fmaf(bflo(sv[0]), sl, acc[0]); r[1] = fmaf(bfhi(sv[0]), sl, acc[1]);
    r[2] = fmaf(bflo(sv[1]), sl, acc[2]); r[3] = fmaf(bfhi(sv[1]), sl, acc[3]);
    r[4] = fmaf(bflo(sv[2]), sl, acc[4]); r[5] = fmaf(bfhi(sv[2]), sl, acc[5]);
    r[6] = fmaf(bflo(sv[3]), sl, acc[6]); r[7] = fmaf(bfhi(sv[3]), sl, acc[7]);
    float4 b0 = *(const float4*)(b + c8);
    float4 b1 = *(const float4*)(b + c8 + 4);
    r[0] = fmaxf(r[0] + b0.x, 0.f); r[1] = fmaxf(r[1] + b0.y, 0.f);
    r[2] = fmaxf(r[2] + b0.z, 0.f); r[3] = fmaxf(r[3] + b0.w, 0.f);
    r[4] = fmaxf(r[4] + b1.x, 0.f); r[5] = fmaxf(r[5] + b1.y, 0.f);
    r[6] = fmaxf(r[6] + b1.z, 0.f); r[7] = fmaxf(r[7] + b1.w, 0.f);

    if (hw) {
        float4 w0 = *(const float4*)(hw + c8);
        float4 w1 = *(const float4*)(hw + c8 + 4);
        float d = r[0] * w0.x + r[1] * w0.y + r[2] * w0.z + r[3] * w0.w
                + r[4] * w1.x + r[5] * w1.y + r[6] * w1.z + r[7] * w1.w;
#pragma unroll
        for (int off = 8; off > 0; off >>= 1) d += __shfl_xor(d, off);
        if (lane == 0) partial[node] = d;
    } else if (g == 0) {
        u32x4 o;
        o[0] = ((u32)f2bf(r[1]) << 16) | (u32)f2bf(r[0]);
        o[1] = ((u32)f2bf(r[3]) << 16) | (u32)f2bf(r[2]);
        o[2] = ((u32)f2bf(r[5]) << 16) | (u32)f2bf(r[4]);
        o[3] = ((u32)f2bf(r[7]) << 16) | (u32)f2bf(r[6]);
        ((u32x4*)h)[node * 16 + l16] = o;
    }
}

// ---------------- head: per-graph segmented sum over sorted batch ----------------

__device__ __forceinline__ int lbound(const void* bt, bool is64, int target) {
    int lo = 0, hi = NN;
    while (lo < hi) {
        int mid = (lo + hi) >> 1;
        long long v = ld_idx(bt, mid, is64);
        if (v < (long long)target) lo = mid + 1; else hi = mid;
    }
    return lo;
}

__global__ __launch_bounds__(256) void k_head(const float* __restrict__ partial,
                                              const void* __restrict__ batch,
                                              const int* __restrict__ flags,
                                              const float* __restrict__ hb,
                                              float* __restrict__ out) {
    int g = blockIdx.x * 4 + (threadIdx.x >> 6);
    if (g >= NG) return;
    int lane = threadIdx.x & 63;
    bool is64 = (flags[1] == 0);
    int lo = lbound(batch, is64, g);
    int hi = lbound(batch, is64, g + 1);
    float s = 0.f;
    for (int i = lo + lane; i < hi; i += 64) s += partial[i];
#pragma unroll
    for (int off = 32; off > 0; off >>= 1) s += __shfl_down(s, off);
    if (lane == 0) out[g] = s + hb[0];
}

extern "C" void kernel_launch(void* const* d_in, const int* in_sizes, int n_in,
                              void* d_out, int out_size, void* d_ws, size_t ws_size,
                              hipStream_t stream) {
    const float* x  = (const float*)d_in[0];
    const void*  ei = d_in[1];
    const void*  bt = d_in[2];
    const float* Ws = (const float*)d_in[3];
    const float* bs = (const float*)d_in[4];
    const float* hw = (const float*)d_in[5];
    const float* hb = (const float*)d_in[6];
    float* out = (float*)d_out;

    char* ws = (char*)d_ws;
    size_t p = 0;
    auto alloc = [&](size_t bytes) { size_t r = p; p += (bytes + 255) & ~(size_t)255; return r; };
    size_t o_flags  = alloc(256);
    size_t o_dinv   = alloc((size_t)NN * 4);
    size_t o_indeg  = alloc((size_t)NN * 4);
    size_t o_rowptr = alloc((size_t)(NN + 1) * 4);
    size_t o_gcur   = alloc((size_t)NBUK * 4);
    size_t o_bsum   = alloc(512 * 4);
    size_t o_part   = alloc((size_t)NN * 4);
    size_t o_bin    = alloc((size_t)NE * 4);
    size_t o_csr    = alloc((size_t)NE * 4);
    size_t o_xb     = alloc((size_t)NN * CH * 2);
    size_t o_tb     = alloc((size_t)NN * CH * 2);
    size_t o_hb     = alloc((size_t)NN * CH * 2);
    size_t o_wt     = alloc((size_t)NL * CH * CH * 2);
    (void)ws_size;  // ~54 MB

    int*   flags  = (int*)(ws + o_flags);
    float* dinv   = (float*)(ws + o_dinv);
    int*   indeg  = (int*)(ws + o_indeg);
    int*   rowptr = (int*)(ws + o_rowptr);
    int*   gcur   = (int*)(ws + o_gcur);
    int*   bsum   = (int*)(ws + o_bsum);
    float* part   = (float*)(ws + o_part);
    u32*   bin    = (u32*)(ws + o_bin);
    u32*   csr    = (u32*)(ws + o_csr);
    u16*   xb     = (u16*)(ws + o_xb);
    u16*   tb     = (u16*)(ws + o_tb);
    u16*   hbuf   = (u16*)(ws + o_hb);
    u16*   Wt     = (u16*)(ws + o_wt);

    const int nb = (NN + 255) / 256;   // 391

    k_zeroi<<<nb, 256, 0, stream>>>(indeg, NN, flags);
    k_detect<<<256, 256, 0, stream>>>((const int*)ei, (const int*)bt, flags);
    k_count<<<(NE + 255) / 256, 256, 0, stream>>>(ei, flags, indeg);
    k_scan1<<<nb, 256, 0, stream>>>(indeg, rowptr, bsum);
    k_scan2<<<1, 512, 0, stream>>>(bsum, nb);
    k_scan3<<<nb, 256, 0, stream>>>(rowptr, bsum, gcur);
    k_dinv_i<<<nb, 256, 0, stream>>>(indeg, dinv);
    k_bin<<<(NE + TILE - 1) / TILE, 256, 0, stream>>>(ei, flags, gcur, bin);
    k_fillb<<<NBUK, BSZ, 0, stream>>>(bin, rowptr, csr);

    k_cvt_x<<<(int)(((long long)NN * CH / 4 + 255) / 256), 256, 0, stream>>>(x, xb);
    k_cvt_w<<<(NL * CH * CH + 255) / 256, 256, 0, stream>>>(Ws, Wt);

    const u16* hin = xb;
    for (int l = 0; l < NL; ++l) {
        bool last = (l == NL - 1);
        k_mm<<<(NN + 127) / 128, 256, 0, stream>>>(hin, Wt + (size_t)l * CH * CH, tb);
        k_aggr<<<(NN + 3) / 4, 256, 0, stream>>>(tb, rowptr, csr, dinv,
                                                 bs + (size_t)l * CH, hbuf,
                                                 last ? hw : nullptr, part);
        hin = hbuf;
    }

    k_head<<<(NG + 3) / 4, 256, 0, stream>>>(part, bt, flags, hb, out);
}

// Round 7
// 431.286 us; speedup vs baseline: 20.8017x; 1.0399x over previous
//
#include <hip/hip_runtime.h>

#define NN 100000
#define NE 1600000
#define CH 128
#define NG 512
#define NL 3
#define BSZ 512                      // nodes per bucket
#define NBUK ((NN + BSZ - 1) / BSZ)  // 196
#define TILE 4096                    // edges per k_bin block

typedef short bf8 __attribute__((ext_vector_type(8)));
typedef float f4 __attribute__((ext_vector_type(4)));
typedef unsigned int u32x4 __attribute__((ext_vector_type(4)));
typedef unsigned short u16;
typedef unsigned int u32;

__device__ __forceinline__ long long ld_idx(const void* p, long long i, bool is64) {
    return is64 ? ((const long long*)p)[i] : (long long)((const int*)p)[i];
}
__device__ __forceinline__ u16 f2bf(float f) {
    u32 u = __float_as_uint(f);
    u += 0x7fffu + ((u >> 16) & 1u);
    return (u16)(u >> 16);
}
__device__ __forceinline__ float bflo(u32 v) { return __uint_as_float(v << 16); }
__device__ __forceinline__ float bfhi(u32 v) { return __uint_as_float(v & 0xffff0000u); }

// zero indeg + flags (merged)
__global__ void k_zeroi(int* p, int n, int* flags) {
    int i = blockIdx.x * blockDim.x + threadIdx.x;
    if (i < n) p[i] = 0;
    if (blockIdx.x == 0 && threadIdx.x < 2) flags[threadIdx.x] = 0;
}

// Detect int64 vs int32 index arrays: for int64 values < 2^31, every odd
// 32-bit word (within the first n_elem words, present either way) is zero.
__global__ void k_detect(const int* __restrict__ ei32, const int* __restrict__ b32, int* flags) {
    int acc_e = 0, acc_b = 0;
    long long stride = (long long)gridDim.x * blockDim.x;
    long long t0 = (long long)blockIdx.x * blockDim.x + threadIdx.x;
    for (long long i = t0; i < NE; i += stride) acc_e |= ei32[2 * i + 1];
    for (long long i = t0; i < NN / 2; i += stride) acc_b |= b32[2 * i + 1];
    if (acc_e) atomicOr(&flags[0], 1);
    if (acc_b) atomicOr(&flags[1], 1);
}

// ---------------- CSR build ----------------

__global__ void k_count(const void* __restrict__ ei, const int* __restrict__ flags,
                        int* __restrict__ indeg) {
    int e = blockIdx.x * blockDim.x + threadIdx.x;
    if (e >= NE) return;
    bool is64 = (flags[0] == 0);
    int d = (int)ld_idx(ei, (long long)NE + e, is64);
    atomicAdd(&indeg[d], 1);
}

__global__ __launch_bounds__(256) void k_scan1(const int* __restrict__ indeg,
                                               int* __restrict__ rowptr,
                                               int* __restrict__ bsum) {
    __shared__ int ws4[4];
    int t = threadIdx.x;
    int i = blockIdx.x * 256 + t;
    int v = (i < NN) ? indeg[i] : 0;
    int x = v;
#pragma unroll
    for (int d = 1; d < 64; d <<= 1) {
        int y = __shfl_up(x, d, 64);
        if ((t & 63) >= d) x += y;
    }
    if ((t & 63) == 63) ws4[t >> 6] = x;
    __syncthreads();
    if (t == 0) {
        int s = 0;
#pragma unroll
        for (int w = 0; w < 4; ++w) { int tmp = ws4[w]; ws4[w] = s; s += tmp; }
        bsum[blockIdx.x] = s;
    }
    __syncthreads();
    if (i < NN) rowptr[i] = x - v + ws4[t >> 6];
}

__global__ __launch_bounds__(512) void k_scan2(int* __restrict__ bsum, int nb) {
    __shared__ int ws8[8];
    int t = threadIdx.x;
    int v = (t < nb) ? bsum[t] : 0;
    int x = v;
#pragma unroll
    for (int d = 1; d < 64; d <<= 1) {
        int y = __shfl_up(x, d, 64);
        if ((t & 63) >= d) x += y;
    }
    if ((t & 63) == 63) ws8[t >> 6] = x;
    __syncthreads();
    if (t == 0) {
        int s = 0;
#pragma unroll
        for (int w = 0; w < 8; ++w) { int tmp = ws8[w]; ws8[w] = s; s += tmp; }
    }
    __syncthreads();
    if (t < nb) bsum[t] = x - v + ws8[t >> 6];
}

// finalize rowptr; init per-bucket cursors; compute dinv (merged)
__global__ void k_scan3(int* __restrict__ rowptr, const int* __restrict__ bsum,
                        int* __restrict__ gcur, const int* __restrict__ indeg,
                        float* __restrict__ dinv) {
    int i = blockIdx.x * 256 + threadIdx.x;
    if (i < NN) {
        int r = rowptr[i] + bsum[blockIdx.x];
        rowptr[i] = r;
        if ((i & (BSZ - 1)) == 0) gcur[i / BSZ] = r;
        dinv[i] = rsqrtf((float)indeg[i] + 1.0f);
    }
    if (i == 0) rowptr[NN] = NE;
}

// ---- pass 1: bin edges by dst bucket, LDS-staged coalesced flush ----
__global__ __launch_bounds__(256) void k_bin(const void* __restrict__ ei,
                                             const int* __restrict__ flags,
                                             int* __restrict__ gcur,
                                             u32* __restrict__ bin) {
    __shared__ u32 stag[TILE];
    __shared__ int cnt[NBUK], loff[NBUK], lcur[NBUK], gb_s[NBUK];
    int tid = threadIdx.x;
    long long e0 = (long long)blockIdx.x * TILE;
    bool is64 = (flags[0] == 0);

    u32 rec[16];
    int bk[16];
#pragma unroll
    for (int k = 0; k < 16; ++k) {
        long long e = e0 + tid + k * 256;
        if (e < NE) {
            int s = (int)ld_idx(ei, e, is64);
            int d = (int)ld_idx(ei, NE + e, is64);
            rec[k] = ((u32)s << 9) | (u32)(d & (BSZ - 1));
            bk[k] = d >> 9;
        } else bk[k] = -1;
    }
    for (int b = tid; b < NBUK; b += 256) { cnt[b] = 0; lcur[b] = 0; }
    __syncthreads();
#pragma unroll
    for (int k = 0; k < 16; ++k)
        if (bk[k] >= 0) atomicAdd(&cnt[bk[k]], 1);
    __syncthreads();
    if (tid == 0) {
        int run = 0;
        for (int b = 0; b < NBUK; ++b) { loff[b] = run; run += cnt[b]; }
    }
    __syncthreads();
    if (tid < NBUK && cnt[tid] > 0) gb_s[tid] = atomicAdd(&gcur[tid], cnt[tid]);
    __syncthreads();
#pragma unroll
    for (int k = 0; k < 16; ++k)
        if (bk[k] >= 0) {
            int pos = loff[bk[k]] + atomicAdd(&lcur[bk[k]], 1);
            stag[pos] = rec[k];
        }
    __syncthreads();
    int wv = tid >> 6, lane = tid & 63;
    for (int b = wv; b < NBUK; b += 4) {
        int n = cnt[b];
        int gb = (n > 0) ? gb_s[b] : 0;
        int lo = loff[b];
        for (int j = lane; j < n; j += 64) bin[gb + j] = stag[lo + j];
    }
}

// ---- pass 2: within each bucket, place records at exact CSR slots ----
__global__ __launch_bounds__(512) void k_fillb(const u32* __restrict__ bin,
                                               const int* __restrict__ rowptr,
                                               u32* __restrict__ csr) {
    __shared__ int lcur[BSZ];
    int b = blockIdx.x;
    int tid = threadIdx.x;
    int nb0 = b * BSZ;
    int node = nb0 + tid;
    lcur[tid] = (node < NN) ? rowptr[node] : 0;
    int gb = rowptr[nb0];
    int ge = rowptr[min(nb0 + BSZ, NN)];
    __syncthreads();
    for (int i = gb + tid; i < ge; i += BSZ) {
        u32 rec = bin[i];
        int n = rec & (BSZ - 1);
        int pos = atomicAdd(&lcur[n], 1);
        csr[pos] = rec >> 9;
    }
}

// ---------------- bf16 conversion (x and Wt merged) ----------------
// Wt[l][c][k] = bf16(Ws[l][k][c])
__global__ void k_cvt(const float* __restrict__ x, u16* __restrict__ xb,
                      const float* __restrict__ Ws, u16* __restrict__ Wt) {
    long long i = ((long long)blockIdx.x * blockDim.x + threadIdx.x) * 4;
    const long long NX = (long long)NN * CH;
    if (i < NX) {
        float4 v = *(const float4*)(x + i);
        ushort4 o;
        o.x = f2bf(v.x); o.y = f2bf(v.y); o.z = f2bf(v.z); o.w = f2bf(v.w);
        *(ushort4*)(xb + i) = o;
    } else {
        int j = (int)(i - NX);
        if (j >= NL * CH * CH) return;
        int l = j >> 14, c = (j >> 7) & 127, k = j & 127;  // k multiple of 4
        ushort4 o;
        o.x = f2bf(Ws[(l << 14) + ((k + 0) << 7) + c]);
        o.y = f2bf(Ws[(l << 14) + ((k + 1) << 7) + c]);
        o.z = f2bf(Ws[(l << 14) + ((k + 2) << 7) + c]);
        o.w = f2bf(Ws[(l << 14) + ((k + 3) << 7) + c]);
        *(ushort4*)(Wt + j) = o;
    }
}

// ---------------- MFMA GEMM: out[N,128] = A[N,128] @ W, all bf16 ----------------
__global__ __launch_bounds__(256) void k_mm(const u16* __restrict__ A,
                                            const u16* __restrict__ Wt,
                                            u16* __restrict__ out) {
    int tid = threadIdx.x;
    int lane = tid & 63;
    int wv = tid >> 6;
    int rbase = blockIdx.x * 128 + wv * 32;
    int lm = lane & 15;
    int lk = (lane >> 4) << 3;

    f4 acc[2][8];
#pragma unroll
    for (int m = 0; m < 2; ++m)
#pragma unroll
        for (int n = 0; n < 8; ++n) acc[m][n] = (f4){0.f, 0.f, 0.f, 0.f};

    int r0 = rbase + lm;      if (r0 >= NN) r0 = NN - 1;
    int r1 = rbase + 16 + lm; if (r1 >= NN) r1 = NN - 1;

#pragma unroll
    for (int kk = 0; kk < 4; ++kk) {
        int ko = kk * 32 + lk;
        bf8 a0 = *(const bf8*)(A + (size_t)r0 * CH + ko);
        bf8 a1 = *(const bf8*)(A + (size_t)r1 * CH + ko);
#pragma unroll
        for (int n = 0; n < 8; ++n) {
            bf8 b = *(const bf8*)(Wt + (n * 16 + lm) * CH + ko);
            acc[0][n] = __builtin_amdgcn_mfma_f32_16x16x32_bf16(a0, b, acc[0][n], 0, 0, 0);
            acc[1][n] = __builtin_amdgcn_mfma_f32_16x16x32_bf16(a1, b, acc[1][n], 0, 0, 0);
        }
    }

#pragma unroll
    for (int m = 0; m < 2; ++m) {
        int rb = rbase + m * 16 + (lane >> 4) * 4;
#pragma unroll
        for (int r = 0; r < 4; ++r) {
            int row = rb + r;
            if (row < NN) {
#pragma unroll
                for (int n = 0; n < 8; ++n)
                    out[(size_t)row * CH + n * 16 + lm] = f2bf(acc[m][n][r]);
            }
        }
    }
}

// ---------------- aggregation: 16 lanes/edge, 16B loads, 4x unrolled MLP ----------------
#define ACC8(v, w) \
    acc[0] = fmaf(bflo(v[0]), w, acc[0]); acc[1] = fmaf(bfhi(v[0]), w, acc[1]); \
    acc[2] = fmaf(bflo(v[1]), w, acc[2]); acc[3] = fmaf(bfhi(v[1]), w, acc[3]); \
    acc[4] = fmaf(bflo(v[2]), w, acc[4]); acc[5] = fmaf(bfhi(v[2]), w, acc[5]); \
    acc[6] = fmaf(bflo(v[3]), w, acc[6]); acc[7] = fmaf(bfhi(v[3]), w, acc[7]);

__global__ __launch_bounds__(256) void k_aggr(const u16* __restrict__ t,
                                              const int* __restrict__ rowptr,
                                              const u32* __restrict__ csr,
                                              const float* __restrict__ dinv,
                                              const float* __restrict__ b,
                                              u16* __restrict__ h,
                                              const float* __restrict__ hw,
                                              float* __restrict__ partial) {
    int node = (blockIdx.x << 2) + (threadIdx.x >> 6);
    if (node >= NN) return;
    int lane = threadIdx.x & 63;
    int g = lane >> 4;
    int l16 = lane & 15;
    int c8 = l16 << 3;
    const u32x4* tp = (const u32x4*)t;

    int beg = rowptr[node], end = rowptr[node + 1];
    float dn = dinv[node];
    float acc[8];
#pragma unroll
    for (int k = 0; k < 8; ++k) acc[k] = 0.f;

    for (int base = beg; base < end; base += 64) {
        int srcv = 0;
        float wl = 0.f;
        if (base + lane < end) {
            srcv = (int)csr[base + lane];
            wl = dinv[srcv] * dn;
        }
        int cnt = min(64, end - base);
        // 4 groups x 4-deep unroll: lanes past cnt carry w=0 (zero contribution)
        for (int j0 = 0; j0 < cnt; j0 += 16) {
            int s0 = __shfl(srcv, j0 + g);
            int s1 = __shfl(srcv, j0 + 4 + g);
            int s2 = __shfl(srcv, j0 + 8 + g);
            int s3 = __shfl(srcv, j0 + 12 + g);
            float w0 = __shfl(wl, j0 + g);
            float w1 = __shfl(wl, j0 + 4 + g);
            float w2 = __shfl(wl, j0 + 8 + g);
            float w3 = __shfl(wl, j0 + 12 + g);
            u32x4 v0 = tp[s0 * 16 + l16];
            u32x4 v1 = tp[s1 * 16 + l16];
            u32x4 v2 = tp[s2 * 16 + l16];
            u32x4 v3 = tp[s3 * 16 + l16];
            ACC8(v0, w0); ACC8(v1, w1); ACC8(v2, w2); ACC8(v3, w3);
        }
    }
#pragma unroll
    for (int k = 0; k < 8; ++k) {
        acc[k] += __shfl_xor(acc[k], 16);
        acc[k] += __shfl_xor(acc[k], 32);
    }
    float sl = dn * dn;
    u32x4 sv = tp[node * 16 + l16];
    float r[8];
    r[0] = fmaf(bflo(sv[0]), sl, acc[0]); r[1] = fmaf(bfhi(sv[0]), sl, acc[1]);
    r[2] = fmaf(bflo(sv[1]), sl, acc[2]); r[3] = fmaf(bfhi(sv[1]), sl, acc[3]);
    r[4] = fmaf(bflo(sv[2]), sl, acc[4]); r[5] = fmaf(bfhi(sv[2]), sl, acc[5]);
    r[6] = fmaf(bflo(sv[3]), sl, acc[6]); r[7] = fmaf(bfhi(sv[3]), sl, acc[7]);
    float4 b0 = *(const float4*)(b + c8);
    float4 b1 = *(const float4*)(b + c8 + 4);
    r[0] = fmaxf(r[0] + b0.x, 0.f); r[1] = fmaxf(r[1] + b0.y, 0.f);
    r[2] = fmaxf(r[2] + b0.z, 0.f); r[3] = fmaxf(r[3] + b0.w, 0.f);
    r[4] = fmaxf(r[4] + b1.x, 0.f); r[5] = fmaxf(r[5] + b1.y, 0.f);
    r[6] = fmaxf(r[6] + b1.z, 0.f); r[7] = fmaxf(r[7] + b1.w, 0.f);

    if (hw) {
        float4 w0 = *(const float4*)(hw + c8);
        float4 w1 = *(const float4*)(hw + c8 + 4);
        float d = r[0] * w0.x + r[1] * w0.y + r[2] * w0.z + r[3] * w0.w
                + r[4] * w1.x + r[5] * w1.y + r[6] * w1.z + r[7] * w1.w;
#pragma unroll
        for (int off = 8; off > 0; off >>= 1) d += __shfl_xor(d, off);
        if (lane == 0) partial[node] = d;
    } else if (g == 0) {
        u32x4 o;
        o[0] = ((u32)f2bf(r[1]) << 16) | (u32)f2bf(r[0]);
        o[1] = ((u32)f2bf(r[3]) << 16) | (u32)f2bf(r[2]);
        o[2] = ((u32)f2bf(r[5]) << 16) | (u32)f2bf(r[4]);
        o[3] = ((u32)f2bf(r[7]) << 16) | (u32)f2bf(r[6]);
        ((u32x4*)h)[node * 16 + l16] = o;
    }
}

// ---------------- head: per-graph segmented sum over sorted batch ----------------

__device__ __forceinline__ int lbound(const void* bt, bool is64, int target) {
    int lo = 0, hi = NN;
    while (lo < hi) {
        int mid = (lo + hi) >> 1;
        long long v = ld_idx(bt, mid, is64);
        if (v < (long long)target) lo = mid + 1; else hi = mid;
    }
    return lo;
}

__global__ __launch_bounds__(256) void k_head(const float* __restrict__ partial,
                                              const void* __restrict__ batch,
                                              const int* __restrict__ flags,
                                              const float* __restrict__ hb,
                                              float* __restrict__ out) {
    int g = blockIdx.x * 4 + (threadIdx.x >> 6);
    if (g >= NG) return;
    int lane = threadIdx.x & 63;
    bool is64 = (flags[1] == 0);
    int lo = lbound(batch, is64, g);
    int hi = lbound(batch, is64, g + 1);
    float s = 0.f;
    for (int i = lo + lane; i < hi; i += 64) s += partial[i];
#pragma unroll
    for (int off = 32; off > 0; off >>= 1) s += __shfl_down(s, off);
    if (lane == 0) out[g] = s + hb[0];
}

extern "C" void kernel_launch(void* const* d_in, const int* in_sizes, int n_in,
                              void* d_out, int out_size, void* d_ws, size_t ws_size,
                              hipStream_t stream) {
    const float* x  = (const float*)d_in[0];
    const void*  ei = d_in[1];
    const void*  bt = d_in[2];
    const float* Ws = (const float*)d_in[3];
    const float* bs = (const float*)d_in[4];
    const float* hw = (const float*)d_in[5];
    const float* hb = (const float*)d_in[6];
    float* out = (float*)d_out;

    char* ws = (char*)d_ws;
    size_t p = 0;
    auto alloc = [&](size_t bytes) { size_t r = p; p += (bytes + 255) & ~(size_t)255; return r; };
    size_t o_flags  = alloc(256);
    size_t o_dinv   = alloc((size_t)NN * 4);
    size_t o_indeg  = alloc((size_t)NN * 4);
    size_t o_rowptr = alloc((size_t)(NN + 1) * 4);
    size_t o_gcur   = alloc((size_t)NBUK * 4);
    size_t o_bsum   = alloc(512 * 4);
    size_t o_part   = alloc((size_t)NN * 4);
    size_t o_bin    = alloc((size_t)NE * 4);
    size_t o_csr    = alloc((size_t)NE * 4);
    size_t o_xb     = alloc((size_t)NN * CH * 2);
    size_t o_tb     = alloc((size_t)NN * CH * 2);
    size_t o_hb     = alloc((size_t)NN * CH * 2);
    size_t o_wt     = alloc((size_t)NL * CH * CH * 2);
    (void)ws_size;  // ~54 MB

    int*   flags  = (int*)(ws + o_flags);
    float* dinv   = (float*)(ws + o_dinv);
    int*   indeg  = (int*)(ws + o_indeg);
    int*   rowptr = (int*)(ws + o_rowptr);
    int*   gcur   = (int*)(ws + o_gcur);
    int*   bsum   = (int*)(ws + o_bsum);
    float* part   = (float*)(ws + o_part);
    u32*   bin    = (u32*)(ws + o_bin);
    u32*   csr    = (u32*)(ws + o_csr);
    u16*   xb     = (u16*)(ws + o_xb);
    u16*   tb     = (u16*)(ws + o_tb);
    u16*   hbuf   = (u16*)(ws + o_hb);
    u16*   Wt     = (u16*)(ws + o_wt);

    const int nb = (NN + 255) / 256;   // 391

    k_zeroi<<<nb, 256, 0, stream>>>(indeg, NN, flags);
    k_detect<<<256, 256, 0, stream>>>((const int*)ei, (const int*)bt, flags);
    k_count<<<(NE + 255) / 256, 256, 0, stream>>>(ei, flags, indeg);
    k_scan1<<<nb, 256, 0, stream>>>(indeg, rowptr, bsum);
    k_scan2<<<1, 512, 0, stream>>>(bsum, nb);
    k_scan3<<<nb, 256, 0, stream>>>(rowptr, bsum, gcur, indeg, dinv);
    k_bin<<<(NE + TILE - 1) / TILE, 256, 0, stream>>>(ei, flags, gcur, bin);
    k_fillb<<<NBUK, BSZ, 0, stream>>>(bin, rowptr, csr);

    long long ncv = (long long)NN * CH / 4 + NL * CH * CH / 4;
    k_cvt<<<(int)((ncv + 255) / 256), 256, 0, stream>>>(x, xb, Ws, Wt);

    const u16* hin = xb;
    for (int l = 0; l < NL; ++l) {
        bool last = (l == NL - 1);
        k_mm<<<(NN + 127) / 128, 256, 0, stream>>>(hin, Wt + (size_t)l * CH * CH, tb);
        k_aggr<<<(NN + 3) / 4, 256, 0, stream>>>(tb, rowptr, csr, dinv,
                                                 bs + (size_t)l * CH, hbuf,
                                                 last ? hw : nullptr, part);
        hin = hbuf;
    }

    k_head<<<(NG + 3) / 4, 256, 0, stream>>>(part, bt, flags, hb, out);
}

// Round 8
// 376.858 us; speedup vs baseline: 23.8060x; 1.1444x over previous
//
#include <hip/hip_runtime.h>

#define NN 100000
#define NE 1600000
#define CH 128
#define NG 512
#define NL 3
#define BSZ 512                      // nodes per bucket
#define NBUK ((NN + BSZ - 1) / BSZ)  // 196
#define TILE 4096                    // edges per k_bin/k_hist block

typedef short bf8 __attribute__((ext_vector_type(8)));
typedef float f4 __attribute__((ext_vector_type(4)));
typedef unsigned int u32x4 __attribute__((ext_vector_type(4)));
typedef unsigned short u16;
typedef unsigned int u32;

__device__ __forceinline__ long long ld_idx(const void* p, long long i, bool is64) {
    return is64 ? ((const long long*)p)[i] : (long long)((const int*)p)[i];
}
__device__ __forceinline__ u16 f2bf(float f) {
    u32 u = __float_as_uint(f);
    u += 0x7fffu + ((u >> 16) & 1u);
    return (u16)(u >> 16);
}
__device__ __forceinline__ float bflo(u32 v) { return __uint_as_float(v << 16); }
__device__ __forceinline__ float bfhi(u32 v) { return __uint_as_float(v & 0xffff0000u); }

// zero bucket counts + flags
__global__ void k_zero(int* bcnt, int* flags) {
    int i = blockIdx.x * blockDim.x + threadIdx.x;
    if (i < NBUK) bcnt[i] = 0;
    if (i < 2) flags[i] = 0;
}

// Detect int64 vs int32 index arrays: for int64 values < 2^31, every odd
// 32-bit word (within the first n_elem words, present either way) is zero.
__global__ void k_detect(const int* __restrict__ ei32, const int* __restrict__ b32, int* flags) {
    int acc_e = 0, acc_b = 0;
    long long stride = (long long)gridDim.x * blockDim.x;
    long long t0 = (long long)blockIdx.x * blockDim.x + threadIdx.x;
    for (long long i = t0; i < NE; i += stride) acc_e |= ei32[2 * i + 1];
    for (long long i = t0; i < NN / 2; i += stride) acc_b |= b32[2 * i + 1];
    if (acc_e) atomicOr(&flags[0], 1);
    if (acc_b) atomicOr(&flags[1], 1);
}

// ---------------- CSR build (bucket-histogram based, no per-node global atomics) ----

// pass A: per-bucket histogram via LDS
__global__ __launch_bounds__(256) void k_hist(const void* __restrict__ ei,
                                              const int* __restrict__ flags,
                                              int* __restrict__ bcnt) {
    __shared__ int cnt[NBUK];
    int tid = threadIdx.x;
    long long e0 = (long long)blockIdx.x * TILE;
    bool is64 = (flags[0] == 0);
    for (int b = tid; b < NBUK; b += 256) cnt[b] = 0;
    __syncthreads();
#pragma unroll
    for (int k = 0; k < 16; ++k) {
        long long e = e0 + tid + k * 256;
        if (e < NE) {
            int d = (int)ld_idx(ei, NE + e, is64);
            atomicAdd(&cnt[d >> 9], 1);
        }
    }
    __syncthreads();
    for (int b = tid; b < NBUK; b += 256)
        if (cnt[b]) atomicAdd(&bcnt[b], cnt[b]);
}

// pass B: exclusive scan of bucket counts -> gbase, gcur
__global__ __launch_bounds__(256) void k_bscan(const int* __restrict__ bcnt,
                                               int* __restrict__ gbase,
                                               int* __restrict__ gcur,
                                               int* __restrict__ rowptr) {
    __shared__ int ws4[4];
    int t = threadIdx.x;
    int v = (t < NBUK) ? bcnt[t] : 0;
    int x = v;
#pragma unroll
    for (int d = 1; d < 64; d <<= 1) {
        int y = __shfl_up(x, d, 64);
        if ((t & 63) >= d) x += y;
    }
    if ((t & 63) == 63) ws4[t >> 6] = x;
    __syncthreads();
    if (t == 0) {
        int s = 0;
#pragma unroll
        for (int w = 0; w < 4; ++w) { int tmp = ws4[w]; ws4[w] = s; s += tmp; }
    }
    __syncthreads();
    int ex = x - v + ws4[t >> 6];
    if (t < NBUK) { gbase[t] = ex; gcur[t] = ex; }
    if (t == NBUK - 1) gbase[NBUK] = ex + v;   // == NE
    if (t == 0) rowptr[NN] = NE;
}

// pass C: bin edges by dst bucket, LDS-staged coalesced flush
__global__ __launch_bounds__(256) void k_bin(const void* __restrict__ ei,
                                             const int* __restrict__ flags,
                                             int* __restrict__ gcur,
                                             u32* __restrict__ bin) {
    __shared__ u32 stag[TILE];
    __shared__ int cnt[NBUK], loff[NBUK], lcur[NBUK], gb_s[NBUK];
    int tid = threadIdx.x;
    long long e0 = (long long)blockIdx.x * TILE;
    bool is64 = (flags[0] == 0);

    u32 rec[16];
    int bk[16];
#pragma unroll
    for (int k = 0; k < 16; ++k) {
        long long e = e0 + tid + k * 256;
        if (e < NE) {
            int s = (int)ld_idx(ei, e, is64);
            int d = (int)ld_idx(ei, NE + e, is64);
            rec[k] = ((u32)s << 9) | (u32)(d & (BSZ - 1));
            bk[k] = d >> 9;
        } else bk[k] = -1;
    }
    for (int b = tid; b < NBUK; b += 256) { cnt[b] = 0; lcur[b] = 0; }
    __syncthreads();
#pragma unroll
    for (int k = 0; k < 16; ++k)
        if (bk[k] >= 0) atomicAdd(&cnt[bk[k]], 1);
    __syncthreads();
    if (tid == 0) {
        int run = 0;
        for (int b = 0; b < NBUK; ++b) { loff[b] = run; run += cnt[b]; }
    }
    __syncthreads();
    if (tid < NBUK && cnt[tid] > 0) gb_s[tid] = atomicAdd(&gcur[tid], cnt[tid]);
    __syncthreads();
#pragma unroll
    for (int k = 0; k < 16; ++k)
        if (bk[k] >= 0) {
            int pos = loff[bk[k]] + atomicAdd(&lcur[bk[k]], 1);
            stag[pos] = rec[k];
        }
    __syncthreads();
    int wv = tid >> 6, lane = tid & 63;
    for (int b = wv; b < NBUK; b += 4) {
        int n = cnt[b];
        int gb = (n > 0) ? gb_s[b] : 0;
        int lo = loff[b];
        for (int j = lane; j < n; j += 64) bin[gb + j] = stag[lo + j];
    }
}

// pass D: per bucket — LDS degree count, block scan -> rowptr/dinv, place records
__global__ __launch_bounds__(512) void k_fillc(const u32* __restrict__ bin,
                                               const int* __restrict__ gbase,
                                               int* __restrict__ rowptr,
                                               float* __restrict__ dinv,
                                               u32* __restrict__ csr) {
    __shared__ int cnt[BSZ];
    __shared__ int lcur[BSZ];
    __shared__ int wsum[8];
    int b = blockIdx.x, tid = threadIdx.x;
    int gb = gbase[b], ge = gbase[b + 1];
    cnt[tid] = 0;
    __syncthreads();
    for (int i = gb + tid; i < ge; i += BSZ)
        atomicAdd(&cnt[bin[i] & (BSZ - 1)], 1);
    __syncthreads();
    int v = cnt[tid];
    int x = v;
#pragma unroll
    for (int d = 1; d < 64; d <<= 1) {
        int y = __shfl_up(x, d, 64);
        if ((tid & 63) >= d) x += y;
    }
    if ((tid & 63) == 63) wsum[tid >> 6] = x;
    __syncthreads();
    if (tid == 0) {
        int s = 0;
#pragma unroll
        for (int w = 0; w < 8; ++w) { int tmp = wsum[w]; wsum[w] = s; s += tmp; }
    }
    __syncthreads();
    int off = gb + x - v + wsum[tid >> 6];    // exclusive prefix within bucket
    int node = b * BSZ + tid;
    if (node < NN) {
        rowptr[node] = off;
        dinv[node] = rsqrtf((float)v + 1.0f);
    }
    lcur[tid] = off;
    __syncthreads();
    for (int i = gb + tid; i < ge; i += BSZ) {
        u32 rec = bin[i];
        int pos = atomicAdd(&lcur[rec & (BSZ - 1)], 1);
        csr[pos] = rec >> 9;
    }
}

// ---------------- bf16 conversion (x and Wt merged) ----------------
// Wt[l][c][k] = bf16(Ws[l][k][c])
__global__ void k_cvt(const float* __restrict__ x, u16* __restrict__ xb,
                      const float* __restrict__ Ws, u16* __restrict__ Wt) {
    long long i = ((long long)blockIdx.x * blockDim.x + threadIdx.x) * 4;
    const long long NX = (long long)NN * CH;
    if (i < NX) {
        float4 v = *(const float4*)(x + i);
        ushort4 o;
        o.x = f2bf(v.x); o.y = f2bf(v.y); o.z = f2bf(v.z); o.w = f2bf(v.w);
        *(ushort4*)(xb + i) = o;
    } else {
        int j = (int)(i - NX);
        if (j >= NL * CH * CH) return;
        int l = j >> 14, c = (j >> 7) & 127, k = j & 127;  // k multiple of 4
        ushort4 o;
        o.x = f2bf(Ws[(l << 14) + ((k + 0) << 7) + c]);
        o.y = f2bf(Ws[(l << 14) + ((k + 1) << 7) + c]);
        o.z = f2bf(Ws[(l << 14) + ((k + 2) << 7) + c]);
        o.w = f2bf(Ws[(l << 14) + ((k + 3) << 7) + c]);
        *(ushort4*)(Wt + j) = o;
    }
}

// ---------------- MFMA GEMM: out[N,128] = A[N,128] @ W, all bf16 ----------------
__global__ __launch_bounds__(256) void k_mm(const u16* __restrict__ A,
                                            const u16* __restrict__ Wt,
                                            u16* __restrict__ out) {
    int tid = threadIdx.x;
    int lane = tid & 63;
    int wv = tid >> 6;
    int rbase = blockIdx.x * 128 + wv * 32;
    int lm = lane & 15;
    int lk = (lane >> 4) << 3;

    f4 acc[2][8];
#pragma unroll
    for (int m = 0; m < 2; ++m)
#pragma unroll
        for (int n = 0; n < 8; ++n) acc[m][n] = (f4){0.f, 0.f, 0.f, 0.f};

    int r0 = rbase + lm;      if (r0 >= NN) r0 = NN - 1;
    int r1 = rbase + 16 + lm; if (r1 >= NN) r1 = NN - 1;

#pragma unroll
    for (int kk = 0; kk < 4; ++kk) {
        int ko = kk * 32 + lk;
        bf8 a0 = *(const bf8*)(A + (size_t)r0 * CH + ko);
        bf8 a1 = *(const bf8*)(A + (size_t)r1 * CH + ko);
#pragma unroll
        for (int n = 0; n < 8; ++n) {
            bf8 b = *(const bf8*)(Wt + (n * 16 + lm) * CH + ko);
            acc[0][n] = __builtin_amdgcn_mfma_f32_16x16x32_bf16(a0, b, acc[0][n], 0, 0, 0);
            acc[1][n] = __builtin_amdgcn_mfma_f32_16x16x32_bf16(a1, b, acc[1][n], 0, 0, 0);
        }
    }

#pragma unroll
    for (int m = 0; m < 2; ++m) {
        int rb = rbase + m * 16 + (lane >> 4) * 4;
#pragma unroll
        for (int r = 0; r < 4; ++r) {
            int row = rb + r;
            if (row < NN) {
#pragma unroll
                for (int n = 0; n < 8; ++n)
                    out[(size_t)row * CH + n * 16 + lm] = f2bf(acc[m][n][r]);
            }
        }
    }
}

// ---------------- aggregation: 16 lanes/edge, 16B loads, 4x unrolled MLP ----------------
#define ACC8(v, w) \
    acc[0] = fmaf(bflo(v[0]), w, acc[0]); acc[1] = fmaf(bfhi(v[0]), w, acc[1]); \
    acc[2] = fmaf(bflo(v[1]), w, acc[2]); acc[3] = fmaf(bfhi(v[1]), w, acc[3]); \
    acc[4] = fmaf(bflo(v[2]), w, acc[4]); acc[5] = fmaf(bfhi(v[2]), w, acc[5]); \
    acc[6] = fmaf(bflo(v[3]), w, acc[6]); acc[7] = fmaf(bfhi(v[3]), w, acc[7]);

__global__ __launch_bounds__(256) void k_aggr(const u16* __restrict__ t,
                                              const int* __restrict__ rowptr,
                                              const u32* __restrict__ csr,
                                              const float* __restrict__ dinv,
                                              const float* __restrict__ b,
                                              u16* __restrict__ h,
                                              const float* __restrict__ hw,
                                              float* __restrict__ partial) {
    int node = (blockIdx.x << 2) + (threadIdx.x >> 6);
    if (node >= NN) return;
    int lane = threadIdx.x & 63;
    int g = lane >> 4;
    int l16 = lane & 15;
    int c8 = l16 << 3;
    const u32x4* tp = (const u32x4*)t;

    int beg = rowptr[node], end = rowptr[node + 1];
    float dn = dinv[node];
    float acc[8];
#pragma unroll
    for (int k = 0; k < 8; ++k) acc[k] = 0.f;

    for (int base = beg; base < end; base += 64) {
        int srcv = 0;
        float wl = 0.f;
        if (base + lane < end) {
            srcv = (int)csr[base + lane];
            wl = dinv[srcv] * dn;
        }
        int cnt = min(64, end - base);
        // 4 groups x 4-deep unroll: lanes past cnt carry w=0 (zero contribution)
        for (int j0 = 0; j0 < cnt; j0 += 16) {
            int s0 = __shfl(srcv, j0 + g);
            int s1 = __shfl(srcv, j0 + 4 + g);
            int s2 = __shfl(srcv, j0 + 8 + g);
            int s3 = __shfl(srcv, j0 + 12 + g);
            float w0 = __shfl(wl, j0 + g);
            float w1 = __shfl(wl, j0 + 4 + g);
            float w2 = __shfl(wl, j0 + 8 + g);
            float w3 = __shfl(wl, j0 + 12 + g);
            u32x4 v0 = tp[s0 * 16 + l16];
            u32x4 v1 = tp[s1 * 16 + l16];
            u32x4 v2 = tp[s2 * 16 + l16];
            u32x4 v3 = tp[s3 * 16 + l16];
            ACC8(v0, w0); ACC8(v1, w1); ACC8(v2, w2); ACC8(v3, w3);
        }
    }
#pragma unroll
    for (int k = 0; k < 8; ++k) {
        acc[k] += __shfl_xor(acc[k], 16);
        acc[k] += __shfl_xor(acc[k], 32);
    }
    float sl = dn * dn;
    u32x4 sv = tp[node * 16 + l16];
    float r[8];
    r[0] = fmaf(bflo(sv[0]), sl, acc[0]); r[1] = fmaf(bfhi(sv[0]), sl, acc[1]);
    r[2] = fmaf(bflo(sv[1]), sl, acc[2]); r[3] = fmaf(bfhi(sv[1]), sl, acc[3]);
    r[4] = fmaf(bflo(sv[2]), sl, acc[4]); r[5] = fmaf(bfhi(sv[2]), sl, acc[5]);
    r[6] = fmaf(bflo(sv[3]), sl, acc[6]); r[7] = fmaf(bfhi(sv[3]), sl, acc[7]);
    float4 b0 = *(const float4*)(b + c8);
    float4 b1 = *(const float4*)(b + c8 + 4);
    r[0] = fmaxf(r[0] + b0.x, 0.f); r[1] = fmaxf(r[1] + b0.y, 0.f);
    r[2] = fmaxf(r[2] + b0.z, 0.f); r[3] = fmaxf(r[3] + b0.w, 0.f);
    r[4] = fmaxf(r[4] + b1.x, 0.f); r[5] = fmaxf(r[5] + b1.y, 0.f);
    r[6] = fmaxf(r[6] + b1.z, 0.f); r[7] = fmaxf(r[7] + b1.w, 0.f);

    if (hw) {
        float4 w0 = *(const float4*)(hw + c8);
        float4 w1 = *(const float4*)(hw + c8 + 4);
        float d = r[0] * w0.x + r[1] * w0.y + r[2] * w0.z + r[3] * w0.w
                + r[4] * w1.x + r[5] * w1.y + r[6] * w1.z + r[7] * w1.w;
#pragma unroll
        for (int off = 8; off > 0; off >>= 1) d += __shfl_xor(d, off);
        if (lane == 0) partial[node] = d;
    } else if (g == 0) {
        u32x4 o;
        o[0] = ((u32)f2bf(r[1]) << 16) | (u32)f2bf(r[0]);
        o[1] = ((u32)f2bf(r[3]) << 16) | (u32)f2bf(r[2]);
        o[2] = ((u32)f2bf(r[5]) << 16) | (u32)f2bf(r[4]);
        o[3] = ((u32)f2bf(r[7]) << 16) | (u32)f2bf(r[6]);
        ((u32x4*)h)[node * 16 + l16] = o;
    }
}

// ---------------- head: per-graph segmented sum over sorted batch ----------------

__device__ __forceinline__ int lbound(const void* bt, bool is64, int target) {
    int lo = 0, hi = NN;
    while (lo < hi) {
        int mid = (lo + hi) >> 1;
        long long v = ld_idx(bt, mid, is64);
        if (v < (long long)target) lo = mid + 1; else hi = mid;
    }
    return lo;
}

__global__ __launch_bounds__(256) void k_head(const float* __restrict__ partial,
                                              const void* __restrict__ batch,
                                              const int* __restrict__ flags,
                                              const float* __restrict__ hb,
                                              float* __restrict__ out) {
    int g = blockIdx.x * 4 + (threadIdx.x >> 6);
    if (g >= NG) return;
    int lane = threadIdx.x & 63;
    bool is64 = (flags[1] == 0);
    int lo = lbound(batch, is64, g);
    int hi = lbound(batch, is64, g + 1);
    float s = 0.f;
    for (int i = lo + lane; i < hi; i += 64) s += partial[i];
#pragma unroll
    for (int off = 32; off > 0; off >>= 1) s += __shfl_down(s, off);
    if (lane == 0) out[g] = s + hb[0];
}

extern "C" void kernel_launch(void* const* d_in, const int* in_sizes, int n_in,
                              void* d_out, int out_size, void* d_ws, size_t ws_size,
                              hipStream_t stream) {
    const float* x  = (const float*)d_in[0];
    const void*  ei = d_in[1];
    const void*  bt = d_in[2];
    const float* Ws = (const float*)d_in[3];
    const float* bs = (const float*)d_in[4];
    const float* hw = (const float*)d_in[5];
    const float* hb = (const float*)d_in[6];
    float* out = (float*)d_out;

    char* ws = (char*)d_ws;
    size_t p = 0;
    auto alloc = [&](size_t bytes) { size_t r = p; p += (bytes + 255) & ~(size_t)255; return r; };
    size_t o_flags  = alloc(256);
    size_t o_dinv   = alloc((size_t)NN * 4);
    size_t o_rowptr = alloc((size_t)(NN + 1) * 4);
    size_t o_bcnt   = alloc((size_t)NBUK * 4);
    size_t o_gbase  = alloc((size_t)(NBUK + 1) * 4);
    size_t o_gcur   = alloc((size_t)NBUK * 4);
    size_t o_part   = alloc((size_t)NN * 4);
    size_t o_bin    = alloc((size_t)NE * 4);
    size_t o_csr    = alloc((size_t)NE * 4);
    size_t o_xb     = alloc((size_t)NN * CH * 2);
    size_t o_tb     = alloc((size_t)NN * CH * 2);
    size_t o_hb     = alloc((size_t)NN * CH * 2);
    size_t o_wt     = alloc((size_t)NL * CH * CH * 2);
    (void)ws_size;  // ~53 MB

    int*   flags  = (int*)(ws + o_flags);
    float* dinv   = (float*)(ws + o_dinv);
    int*   rowptr = (int*)(ws + o_rowptr);
    int*   bcnt   = (int*)(ws + o_bcnt);
    int*   gbase  = (int*)(ws + o_gbase);
    int*   gcur   = (int*)(ws + o_gcur);
    float* part   = (float*)(ws + o_part);
    u32*   bin    = (u32*)(ws + o_bin);
    u32*   csr    = (u32*)(ws + o_csr);
    u16*   xb     = (u16*)(ws + o_xb);
    u16*   tb     = (u16*)(ws + o_tb);
    u16*   hbuf   = (u16*)(ws + o_hb);
    u16*   Wt     = (u16*)(ws + o_wt);

    k_zero<<<1, 256, 0, stream>>>(bcnt, flags);
    k_detect<<<256, 256, 0, stream>>>((const int*)ei, (const int*)bt, flags);
    k_hist<<<(NE + TILE - 1) / TILE, 256, 0, stream>>>(ei, flags, bcnt);
    k_bscan<<<1, 256, 0, stream>>>(bcnt, gbase, gcur, rowptr);
    k_bin<<<(NE + TILE - 1) / TILE, 256, 0, stream>>>(ei, flags, gcur, bin);
    k_fillc<<<NBUK, BSZ, 0, stream>>>(bin, gbase, rowptr, dinv, csr);

    long long ncv = (long long)NN * CH / 4 + NL * CH * CH / 4;
    k_cvt<<<(int)((ncv + 255) / 256), 256, 0, stream>>>(x, xb, Ws, Wt);

    const u16* hin = xb;
    for (int l = 0; l < NL; ++l) {
        bool last = (l == NL - 1);
        k_mm<<<(NN + 127) / 128, 256, 0, stream>>>(hin, Wt + (size_t)l * CH * CH, tb);
        k_aggr<<<(NN + 3) / 4, 256, 0, stream>>>(tb, rowptr, csr, dinv,
                                                 bs + (size_t)l * CH, hbuf,
                                                 last ? hw : nullptr, part);
        hin = hbuf;
    }

    k_head<<<(NG + 3) / 4, 256, 0, stream>>>(part, bt, flags, hb, out);
}

// Round 9
// 373.222 us; speedup vs baseline: 24.0379x; 1.0097x over previous
//
#include <hip/hip_runtime.h>

#define NN 100000
#define NE 1600000
#define CH 128
#define NG 512
#define NL 3
#define BSZ 512                      // nodes per bucket
#define NBUK ((NN + BSZ - 1) / BSZ)  // 196
#define TILE 4096                    // edges per k_bin/k_hist block

typedef short bf8 __attribute__((ext_vector_type(8)));
typedef float f4 __attribute__((ext_vector_type(4)));
typedef unsigned int u32x4 __attribute__((ext_vector_type(4)));
typedef unsigned short u16;
typedef unsigned int u32;

__device__ __forceinline__ long long ld_idx(const void* p, long long i, bool is64) {
    return is64 ? ((const long long*)p)[i] : (long long)((const int*)p)[i];
}
__device__ __forceinline__ u16 f2bf(float f) {
    u32 u = __float_as_uint(f);
    u += 0x7fffu + ((u >> 16) & 1u);
    return (u16)(u >> 16);
}
__device__ __forceinline__ float bflo(u32 v) { return __uint_as_float(v << 16); }
__device__ __forceinline__ float bfhi(u32 v) { return __uint_as_float(v & 0xffff0000u); }

// zero bucket counts + flags
__global__ void k_zero(int* bcnt, int* flags) {
    int i = blockIdx.x * blockDim.x + threadIdx.x;
    if (i < NBUK) bcnt[i] = 0;
    if (i < 2) flags[i] = 0;
}

// Detect int64 vs int32 index arrays: for int64 values < 2^31, every odd
// 32-bit word is zero. Prefix of 262144 edges suffices (any nonzero odd word
// proves int32; 131k random nonneg indices can't be all-zero for this input).
__global__ void k_detect(const int* __restrict__ ei32, const int* __restrict__ b32, int* flags) {
    int acc_e = 0, acc_b = 0;
    long long stride = (long long)gridDim.x * blockDim.x;
    long long t0 = (long long)blockIdx.x * blockDim.x + threadIdx.x;
    for (long long i = t0; i < (1 << 18); i += stride) acc_e |= ei32[2 * i + 1];
    for (long long i = t0; i < NN / 2; i += stride) acc_b |= b32[2 * i + 1];
    if (acc_e) atomicOr(&flags[0], 1);
    if (acc_b) atomicOr(&flags[1], 1);
}

// ---------------- CSR build (bucket-histogram based, no per-node global atomics) ----

// pass A: per-bucket histogram via LDS
__global__ __launch_bounds__(256) void k_hist(const void* __restrict__ ei,
                                              const int* __restrict__ flags,
                                              int* __restrict__ bcnt) {
    __shared__ int cnt[NBUK];
    int tid = threadIdx.x;
    long long e0 = (long long)blockIdx.x * TILE;
    bool is64 = (flags[0] == 0);
    for (int b = tid; b < NBUK; b += 256) cnt[b] = 0;
    __syncthreads();
#pragma unroll
    for (int k = 0; k < 16; ++k) {
        long long e = e0 + tid + k * 256;
        if (e < NE) {
            int d = (int)ld_idx(ei, NE + e, is64);
            atomicAdd(&cnt[d >> 9], 1);
        }
    }
    __syncthreads();
    for (int b = tid; b < NBUK; b += 256)
        if (cnt[b]) atomicAdd(&bcnt[b], cnt[b]);
}

// pass B: exclusive scan of bucket counts -> gbase, gcur
__global__ __launch_bounds__(256) void k_bscan(const int* __restrict__ bcnt,
                                               int* __restrict__ gbase,
                                               int* __restrict__ gcur,
                                               int* __restrict__ rowptr) {
    __shared__ int ws4[4];
    int t = threadIdx.x;
    int v = (t < NBUK) ? bcnt[t] : 0;
    int x = v;
#pragma unroll
    for (int d = 1; d < 64; d <<= 1) {
        int y = __shfl_up(x, d, 64);
        if ((t & 63) >= d) x += y;
    }
    if ((t & 63) == 63) ws4[t >> 6] = x;
    __syncthreads();
    if (t == 0) {
        int s = 0;
#pragma unroll
        for (int w = 0; w < 4; ++w) { int tmp = ws4[w]; ws4[w] = s; s += tmp; }
    }
    __syncthreads();
    int ex = x - v + ws4[t >> 6];
    if (t < NBUK) { gbase[t] = ex; gcur[t] = ex; }
    if (t == NBUK - 1) gbase[NBUK] = ex + v;   // == NE
    if (t == 0) rowptr[NN] = NE;
}

// pass C: bin edges by dst bucket, LDS-staged coalesced flush
__global__ __launch_bounds__(256) void k_bin(const void* __restrict__ ei,
                                             const int* __restrict__ flags,
                                             int* __restrict__ gcur,
                                             u32* __restrict__ bin) {
    __shared__ u32 stag[TILE];
    __shared__ int cnt[NBUK], loff[NBUK], lcur[NBUK], gb_s[NBUK];
    int tid = threadIdx.x;
    long long e0 = (long long)blockIdx.x * TILE;
    bool is64 = (flags[0] == 0);

    u32 rec[16];
    int bk[16];
#pragma unroll
    for (int k = 0; k < 16; ++k) {
        long long e = e0 + tid + k * 256;
        if (e < NE) {
            int s = (int)ld_idx(ei, e, is64);
            int d = (int)ld_idx(ei, NE + e, is64);
            rec[k] = ((u32)s << 9) | (u32)(d & (BSZ - 1));
            bk[k] = d >> 9;
        } else bk[k] = -1;
    }
    for (int b = tid; b < NBUK; b += 256) { cnt[b] = 0; lcur[b] = 0; }
    __syncthreads();
#pragma unroll
    for (int k = 0; k < 16; ++k)
        if (bk[k] >= 0) atomicAdd(&cnt[bk[k]], 1);
    __syncthreads();
    if (tid == 0) {
        int run = 0;
        for (int b = 0; b < NBUK; ++b) { loff[b] = run; run += cnt[b]; }
    }
    __syncthreads();
    if (tid < NBUK && cnt[tid] > 0) gb_s[tid] = atomicAdd(&gcur[tid], cnt[tid]);
    __syncthreads();
#pragma unroll
    for (int k = 0; k < 16; ++k)
        if (bk[k] >= 0) {
            int pos = loff[bk[k]] + atomicAdd(&lcur[bk[k]], 1);
            stag[pos] = rec[k];
        }
    __syncthreads();
    int wv = tid >> 6, lane = tid & 63;
    for (int b = wv; b < NBUK; b += 4) {
        int n = cnt[b];
        int gb = (n > 0) ? gb_s[b] : 0;
        int lo = loff[b];
        for (int j = lane; j < n; j += 64) bin[gb + j] = stag[lo + j];
    }
}

// pass D: per bucket — LDS degree count, block scan -> rowptr/dinv, place records
__global__ __launch_bounds__(512) void k_fillc(const u32* __restrict__ bin,
                                               const int* __restrict__ gbase,
                                               int* __restrict__ rowptr,
                                               float* __restrict__ dinv,
                                               u32* __restrict__ csr) {
    __shared__ int cnt[BSZ];
    __shared__ int lcur[BSZ];
    __shared__ int wsum[8];
    int b = blockIdx.x, tid = threadIdx.x;
    int gb = gbase[b], ge = gbase[b + 1];
    cnt[tid] = 0;
    __syncthreads();
    for (int i = gb + tid; i < ge; i += BSZ)
        atomicAdd(&cnt[bin[i] & (BSZ - 1)], 1);
    __syncthreads();
    int v = cnt[tid];
    int x = v;
#pragma unroll
    for (int d = 1; d < 64; d <<= 1) {
        int y = __shfl_up(x, d, 64);
        if ((tid & 63) >= d) x += y;
    }
    if ((tid & 63) == 63) wsum[tid >> 6] = x;
    __syncthreads();
    if (tid == 0) {
        int s = 0;
#pragma unroll
        for (int w = 0; w < 8; ++w) { int tmp = wsum[w]; wsum[w] = s; s += tmp; }
    }
    __syncthreads();
    int off = gb + x - v + wsum[tid >> 6];    // exclusive prefix within bucket
    int node = b * BSZ + tid;
    if (node < NN) {
        rowptr[node] = off;
        dinv[node] = rsqrtf((float)v + 1.0f);
    }
    lcur[tid] = off;
    __syncthreads();
    for (int i = gb + tid; i < ge; i += BSZ) {
        u32 rec = bin[i];
        int pos = atomicAdd(&lcur[rec & (BSZ - 1)], 1);
        csr[pos] = rec >> 9;
    }
}

// ---------------- bf16 conversion (x and Wt merged) ----------------
// Wt[l][c][k] = bf16(Ws[l][k][c])
__global__ void k_cvt(const float* __restrict__ x, u16* __restrict__ xb,
                      const float* __restrict__ Ws, u16* __restrict__ Wt) {
    long long i = ((long long)blockIdx.x * blockDim.x + threadIdx.x) * 4;
    const long long NX = (long long)NN * CH;
    if (i < NX) {
        float4 v = *(const float4*)(x + i);
        ushort4 o;
        o.x = f2bf(v.x); o.y = f2bf(v.y); o.z = f2bf(v.z); o.w = f2bf(v.w);
        *(ushort4*)(xb + i) = o;
    } else {
        int j = (int)(i - NX);
        if (j >= NL * CH * CH) return;
        int l = j >> 14, c = (j >> 7) & 127, k = j & 127;  // k multiple of 4
        ushort4 o;
        o.x = f2bf(Ws[(l << 14) + ((k + 0) << 7) + c]);
        o.y = f2bf(Ws[(l << 14) + ((k + 1) << 7) + c]);
        o.z = f2bf(Ws[(l << 14) + ((k + 2) << 7) + c]);
        o.w = f2bf(Ws[(l << 14) + ((k + 3) << 7) + c]);
        *(ushort4*)(Wt + j) = o;
    }
}

// ---------------- MFMA GEMM: out[N,128] = A[N,128] @ W, all bf16 ----------------
__global__ __launch_bounds__(256) void k_mm(const u16* __restrict__ A,
                                            const u16* __restrict__ Wt,
                                            u16* __restrict__ out) {
    int tid = threadIdx.x;
    int lane = tid & 63;
    int wv = tid >> 6;
    int rbase = blockIdx.x * 128 + wv * 32;
    int lm = lane & 15;
    int lk = (lane >> 4) << 3;

    f4 acc[2][8];
#pragma unroll
    for (int m = 0; m < 2; ++m)
#pragma unroll
        for (int n = 0; n < 8; ++n) acc[m][n] = (f4){0.f, 0.f, 0.f, 0.f};

    int r0 = rbase + lm;      if (r0 >= NN) r0 = NN - 1;
    int r1 = rbase + 16 + lm; if (r1 >= NN) r1 = NN - 1;

#pragma unroll
    for (int kk = 0; kk < 4; ++kk) {
        int ko = kk * 32 + lk;
        bf8 a0 = *(const bf8*)(A + (size_t)r0 * CH + ko);
        bf8 a1 = *(const bf8*)(A + (size_t)r1 * CH + ko);
#pragma unroll
        for (int n = 0; n < 8; ++n) {
            bf8 b = *(const bf8*)(Wt + (n * 16 + lm) * CH + ko);
            acc[0][n] = __builtin_amdgcn_mfma_f32_16x16x32_bf16(a0, b, acc[0][n], 0, 0, 0);
            acc[1][n] = __builtin_amdgcn_mfma_f32_16x16x32_bf16(a1, b, acc[1][n], 0, 0, 0);
        }
    }

#pragma unroll
    for (int m = 0; m < 2; ++m) {
        int rb = rbase + m * 16 + (lane >> 4) * 4;
#pragma unroll
        for (int r = 0; r < 4; ++r) {
            int row = rb + r;
            if (row < NN) {
#pragma unroll
                for (int n = 0; n < 8; ++n)
                    out[(size_t)row * CH + n * 16 + lm] = f2bf(acc[m][n][r]);
            }
        }
    }
}

// ---------------- aggregation v3: 16-lane group per node, no shuffles ----------------
// Block = 256 threads = 16 nodes. Group's 16 lanes broadcast-read csr/dinv
// (same address) and issue 4 independent 256B row gathers -> 16 loads in
// flight per wave. dn factored out of the inner loop.
#define ACC8W(v, w) \
    acc[0] = fmaf(bflo(v[0]), w, acc[0]); acc[1] = fmaf(bfhi(v[0]), w, acc[1]); \
    acc[2] = fmaf(bflo(v[1]), w, acc[2]); acc[3] = fmaf(bfhi(v[1]), w, acc[3]); \
    acc[4] = fmaf(bflo(v[2]), w, acc[4]); acc[5] = fmaf(bfhi(v[2]), w, acc[5]); \
    acc[6] = fmaf(bflo(v[3]), w, acc[6]); acc[7] = fmaf(bfhi(v[3]), w, acc[7]);

__global__ __launch_bounds__(256) void k_aggr(const u16* __restrict__ t,
                                              const int* __restrict__ rowptr,
                                              const u32* __restrict__ csr,
                                              const float* __restrict__ dinv,
                                              const float* __restrict__ b,
                                              u16* __restrict__ h,
                                              const float* __restrict__ hw,
                                              float* __restrict__ partial) {
    int node = blockIdx.x * 16 + (threadIdx.x >> 4);
    if (node >= NN) return;
    int l16 = threadIdx.x & 15;
    int c8 = l16 << 3;
    const u32x4* tp = (const u32x4*)t;

    int beg = rowptr[node], end = rowptr[node + 1];
    float dn = dinv[node];
    float acc[8];
#pragma unroll
    for (int k = 0; k < 8; ++k) acc[k] = 0.f;

    int j = beg;
    for (; j + 4 <= end; j += 4) {
        int s0 = (int)csr[j], s1 = (int)csr[j + 1];
        int s2 = (int)csr[j + 2], s3 = (int)csr[j + 3];
        float w0 = dinv[s0], w1 = dinv[s1], w2 = dinv[s2], w3 = dinv[s3];
        u32x4 v0 = tp[s0 * 16 + l16];
        u32x4 v1 = tp[s1 * 16 + l16];
        u32x4 v2 = tp[s2 * 16 + l16];
        u32x4 v3 = tp[s3 * 16 + l16];
        ACC8W(v0, w0); ACC8W(v1, w1); ACC8W(v2, w2); ACC8W(v3, w3);
    }
    for (; j < end; ++j) {
        int s = (int)csr[j];
        float w = dinv[s];
        u32x4 v = tp[s * 16 + l16];
        ACC8W(v, w);
    }

    // r = (acc + dn*t_self) * dn + bias, relu
    u32x4 sv = tp[node * 16 + l16];
    float4 b0 = *(const float4*)(b + c8);
    float4 b1 = *(const float4*)(b + c8 + 4);
    float r[8];
    r[0] = fmaxf(fmaf(fmaf(bflo(sv[0]), dn, acc[0]), dn, b0.x), 0.f);
    r[1] = fmaxf(fmaf(fmaf(bfhi(sv[0]), dn, acc[1]), dn, b0.y), 0.f);
    r[2] = fmaxf(fmaf(fmaf(bflo(sv[1]), dn, acc[2]), dn, b0.z), 0.f);
    r[3] = fmaxf(fmaf(fmaf(bfhi(sv[1]), dn, acc[3]), dn, b0.w), 0.f);
    r[4] = fmaxf(fmaf(fmaf(bflo(sv[2]), dn, acc[4]), dn, b1.x), 0.f);
    r[5] = fmaxf(fmaf(fmaf(bfhi(sv[2]), dn, acc[5]), dn, b1.y), 0.f);
    r[6] = fmaxf(fmaf(fmaf(bflo(sv[3]), dn, acc[6]), dn, b1.z), 0.f);
    r[7] = fmaxf(fmaf(fmaf(bfhi(sv[3]), dn, acc[7]), dn, b1.w), 0.f);

    if (hw) {
        float4 w0 = *(const float4*)(hw + c8);
        float4 w1 = *(const float4*)(hw + c8 + 4);
        float d = r[0] * w0.x + r[1] * w0.y + r[2] * w0.z + r[3] * w0.w
                + r[4] * w1.x + r[5] * w1.y + r[6] * w1.z + r[7] * w1.w;
#pragma unroll
        for (int off = 8; off > 0; off >>= 1) d += __shfl_xor(d, off);
        if (l16 == 0) partial[node] = d;
    } else {
        u32x4 o;
        o[0] = ((u32)f2bf(r[1]) << 16) | (u32)f2bf(r[0]);
        o[1] = ((u32)f2bf(r[3]) << 16) | (u32)f2bf(r[2]);
        o[2] = ((u32)f2bf(r[5]) << 16) | (u32)f2bf(r[4]);
        o[3] = ((u32)f2bf(r[7]) << 16) | (u32)f2bf(r[6]);
        ((u32x4*)h)[node * 16 + l16] = o;
    }
}

// ---------------- head: per-graph segmented sum over sorted batch ----------------

__device__ __forceinline__ int lbound(const void* bt, bool is64, int target) {
    int lo = 0, hi = NN;
    while (lo < hi) {
        int mid = (lo + hi) >> 1;
        long long v = ld_idx(bt, mid, is64);
        if (v < (long long)target) lo = mid + 1; else hi = mid;
    }
    return lo;
}

__global__ __launch_bounds__(256) void k_head(const float* __restrict__ partial,
                                              const void* __restrict__ batch,
                                              const int* __restrict__ flags,
                                              const float* __restrict__ hb,
                                              float* __restrict__ out) {
    int g = blockIdx.x * 4 + (threadIdx.x >> 6);
    if (g >= NG) return;
    int lane = threadIdx.x & 63;
    bool is64 = (flags[1] == 0);
    int lo = lbound(batch, is64, g);
    int hi = lbound(batch, is64, g + 1);
    float s = 0.f;
    for (int i = lo + lane; i < hi; i += 64) s += partial[i];
#pragma unroll
    for (int off = 32; off > 0; off >>= 1) s += __shfl_down(s, off);
    if (lane == 0) out[g] = s + hb[0];
}

extern "C" void kernel_launch(void* const* d_in, const int* in_sizes, int n_in,
                              void* d_out, int out_size, void* d_ws, size_t ws_size,
                              hipStream_t stream) {
    const float* x  = (const float*)d_in[0];
    const void*  ei = d_in[1];
    const void*  bt = d_in[2];
    const float* Ws = (const float*)d_in[3];
    const float* bs = (const float*)d_in[4];
    const float* hw = (const float*)d_in[5];
    const float* hb = (const float*)d_in[6];
    float* out = (float*)d_out;

    char* ws = (char*)d_ws;
    size_t p = 0;
    auto alloc = [&](size_t bytes) { size_t r = p; p += (bytes + 255) & ~(size_t)255; return r; };
    size_t o_flags  = alloc(256);
    size_t o_dinv   = alloc((size_t)NN * 4);
    size_t o_rowptr = alloc((size_t)(NN + 1) * 4);
    size_t o_bcnt   = alloc((size_t)NBUK * 4);
    size_t o_gbase  = alloc((size_t)(NBUK + 1) * 4);
    size_t o_gcur   = alloc((size_t)NBUK * 4);
    size_t o_part   = alloc((size_t)NN * 4);
    size_t o_bin    = alloc((size_t)NE * 4);
    size_t o_csr    = alloc((size_t)NE * 4);
    size_t o_xb     = alloc((size_t)NN * CH * 2);
    size_t o_tb     = alloc((size_t)NN * CH * 2);
    size_t o_hb     = alloc((size_t)NN * CH * 2);
    size_t o_wt     = alloc((size_t)NL * CH * CH * 2);
    (void)ws_size;  // ~53 MB

    int*   flags  = (int*)(ws + o_flags);
    float* dinv   = (float*)(ws + o_dinv);
    int*   rowptr = (int*)(ws + o_rowptr);
    int*   bcnt   = (int*)(ws + o_bcnt);
    int*   gbase  = (int*)(ws + o_gbase);
    int*   gcur   = (int*)(ws + o_gcur);
    float* part   = (float*)(ws + o_part);
    u32*   bin    = (u32*)(ws + o_bin);
    u32*   csr    = (u32*)(ws + o_csr);
    u16*   xb     = (u16*)(ws + o_xb);
    u16*   tb     = (u16*)(ws + o_tb);
    u16*   hbuf   = (u16*)(ws + o_hb);
    u16*   Wt     = (u16*)(ws + o_wt);

    k_zero<<<1, 256, 0, stream>>>(bcnt, flags);
    k_detect<<<256, 256, 0, stream>>>((const int*)ei, (const int*)bt, flags);
    k_hist<<<(NE + TILE - 1) / TILE, 256, 0, stream>>>(ei, flags, bcnt);
    k_bscan<<<1, 256, 0, stream>>>(bcnt, gbase, gcur, rowptr);
    k_bin<<<(NE + TILE - 1) / TILE, 256, 0, stream>>>(ei, flags, gcur, bin);
    k_fillc<<<NBUK, BSZ, 0, stream>>>(bin, gbase, rowptr, dinv, csr);

    long long ncv = (long long)NN * CH / 4 + NL * CH * CH / 4;
    k_cvt<<<(int)((ncv + 255) / 256), 256, 0, stream>>>(x, xb, Ws, Wt);

    const u16* hin = xb;
    for (int l = 0; l < NL; ++l) {
        bool last = (l == NL - 1);
        k_mm<<<(NN + 127) / 128, 256, 0, stream>>>(hin, Wt + (size_t)l * CH * CH, tb);
        k_aggr<<<(NN + 15) / 16, 256, 0, stream>>>(tb, rowptr, csr, dinv,
                                                   bs + (size_t)l * CH, hbuf,
                                                   last ? hw : nullptr, part);
        hin = hbuf;
    }

    k_head<<<(NG + 3) / 4, 256, 0, stream>>>(part, bt, flags, hb, out);
}

// Round 10
// 367.120 us; speedup vs baseline: 24.4375x; 1.0166x over previous
//
#include <hip/hip_runtime.h>

#define NN 100000
#define NE 1600000
#define CH 128
#define NG 512
#define NL 3
#define BSZ 512                      // nodes per bucket
#define NBUK ((NN + BSZ - 1) / BSZ)  // 196
#define TILE 4096                    // edges per k_bin/k_hist block

typedef short bf8 __attribute__((ext_vector_type(8)));
typedef float f4 __attribute__((ext_vector_type(4)));
typedef unsigned int u32x4 __attribute__((ext_vector_type(4)));
typedef unsigned short u16;
typedef unsigned int u32;

__device__ __forceinline__ long long ld_idx(const void* p, long long i, bool is64) {
    return is64 ? ((const long long*)p)[i] : (long long)((const int*)p)[i];
}
__device__ __forceinline__ u16 f2bf(float f) {
    u32 u = __float_as_uint(f);
    u += 0x7fffu + ((u >> 16) & 1u);
    return (u16)(u >> 16);
}
__device__ __forceinline__ float bflo(u32 v) { return __uint_as_float(v << 16); }
__device__ __forceinline__ float bfhi(u32 v) { return __uint_as_float(v & 0xffff0000u); }

// zero bucket counts + flags
__global__ void k_zero(int* bcnt, int* flags) {
    int i = blockIdx.x * blockDim.x + threadIdx.x;
    if (i < NBUK) bcnt[i] = 0;
    if (i < 2) flags[i] = 0;
}

// Detect int64 vs int32 index arrays (prefix suffices)
__global__ void k_detect(const int* __restrict__ ei32, const int* __restrict__ b32, int* flags) {
    int acc_e = 0, acc_b = 0;
    long long stride = (long long)gridDim.x * blockDim.x;
    long long t0 = (long long)blockIdx.x * blockDim.x + threadIdx.x;
    for (long long i = t0; i < (1 << 18); i += stride) acc_e |= ei32[2 * i + 1];
    for (long long i = t0; i < NN / 2; i += stride) acc_b |= b32[2 * i + 1];
    if (acc_e) atomicOr(&flags[0], 1);
    if (acc_b) atomicOr(&flags[1], 1);
}

// ---------------- CSR build (bucket-histogram based) ----------------

__global__ __launch_bounds__(256) void k_hist(const void* __restrict__ ei,
                                              const int* __restrict__ flags,
                                              int* __restrict__ bcnt) {
    __shared__ int cnt[NBUK];
    int tid = threadIdx.x;
    long long e0 = (long long)blockIdx.x * TILE;
    bool is64 = (flags[0] == 0);
    for (int b = tid; b < NBUK; b += 256) cnt[b] = 0;
    __syncthreads();
#pragma unroll
    for (int k = 0; k < 16; ++k) {
        long long e = e0 + tid + k * 256;
        if (e < NE) {
            int d = (int)ld_idx(ei, NE + e, is64);
            atomicAdd(&cnt[d >> 9], 1);
        }
    }
    __syncthreads();
    for (int b = tid; b < NBUK; b += 256)
        if (cnt[b]) atomicAdd(&bcnt[b], cnt[b]);
}

__global__ __launch_bounds__(256) void k_bscan(const int* __restrict__ bcnt,
                                               int* __restrict__ gbase,
                                               int* __restrict__ gcur,
                                               int* __restrict__ rowptr) {
    __shared__ int ws4[4];
    int t = threadIdx.x;
    int v = (t < NBUK) ? bcnt[t] : 0;
    int x = v;
#pragma unroll
    for (int d = 1; d < 64; d <<= 1) {
        int y = __shfl_up(x, d, 64);
        if ((t & 63) >= d) x += y;
    }
    if ((t & 63) == 63) ws4[t >> 6] = x;
    __syncthreads();
    if (t == 0) {
        int s = 0;
#pragma unroll
        for (int w = 0; w < 4; ++w) { int tmp = ws4[w]; ws4[w] = s; s += tmp; }
    }
    __syncthreads();
    int ex = x - v + ws4[t >> 6];
    if (t < NBUK) { gbase[t] = ex; gcur[t] = ex; }
    if (t == NBUK - 1) gbase[NBUK] = ex + v;   // == NE
    if (t == 0) rowptr[NN] = NE;
}

__global__ __launch_bounds__(256) void k_bin(const void* __restrict__ ei,
                                             const int* __restrict__ flags,
                                             int* __restrict__ gcur,
                                             u32* __restrict__ bin) {
    __shared__ u32 stag[TILE];
    __shared__ int cnt[NBUK], loff[NBUK], lcur[NBUK], gb_s[NBUK];
    int tid = threadIdx.x;
    long long e0 = (long long)blockIdx.x * TILE;
    bool is64 = (flags[0] == 0);

    u32 rec[16];
    int bk[16];
#pragma unroll
    for (int k = 0; k < 16; ++k) {
        long long e = e0 + tid + k * 256;
        if (e < NE) {
            int s = (int)ld_idx(ei, e, is64);
            int d = (int)ld_idx(ei, NE + e, is64);
            rec[k] = ((u32)s << 9) | (u32)(d & (BSZ - 1));
            bk[k] = d >> 9;
        } else bk[k] = -1;
    }
    for (int b = tid; b < NBUK; b += 256) { cnt[b] = 0; lcur[b] = 0; }
    __syncthreads();
#pragma unroll
    for (int k = 0; k < 16; ++k)
        if (bk[k] >= 0) atomicAdd(&cnt[bk[k]], 1);
    __syncthreads();
    if (tid == 0) {
        int run = 0;
        for (int b = 0; b < NBUK; ++b) { loff[b] = run; run += cnt[b]; }
    }
    __syncthreads();
    if (tid < NBUK && cnt[tid] > 0) gb_s[tid] = atomicAdd(&gcur[tid], cnt[tid]);
    __syncthreads();
#pragma unroll
    for (int k = 0; k < 16; ++k)
        if (bk[k] >= 0) {
            int pos = loff[bk[k]] + atomicAdd(&lcur[bk[k]], 1);
            stag[pos] = rec[k];
        }
    __syncthreads();
    int wv = tid >> 6, lane = tid & 63;
    for (int b = wv; b < NBUK; b += 4) {
        int n = cnt[b];
        int gb = (n > 0) ? gb_s[b] : 0;
        int lo = loff[b];
        for (int j = lane; j < n; j += 64) bin[gb + j] = stag[lo + j];
    }
}

__global__ __launch_bounds__(512) void k_fillc(const u32* __restrict__ bin,
                                               const int* __restrict__ gbase,
                                               int* __restrict__ rowptr,
                                               float* __restrict__ dinv,
                                               u32* __restrict__ csr) {
    __shared__ int cnt[BSZ];
    __shared__ int lcur[BSZ];
    __shared__ int wsum[8];
    int b = blockIdx.x, tid = threadIdx.x;
    int gb = gbase[b], ge = gbase[b + 1];
    cnt[tid] = 0;
    __syncthreads();
    for (int i = gb + tid; i < ge; i += BSZ)
        atomicAdd(&cnt[bin[i] & (BSZ - 1)], 1);
    __syncthreads();
    int v = cnt[tid];
    int x = v;
#pragma unroll
    for (int d = 1; d < 64; d <<= 1) {
        int y = __shfl_up(x, d, 64);
        if ((tid & 63) >= d) x += y;
    }
    if ((tid & 63) == 63) wsum[tid >> 6] = x;
    __syncthreads();
    if (tid == 0) {
        int s = 0;
#pragma unroll
        for (int w = 0; w < 8; ++w) { int tmp = wsum[w]; wsum[w] = s; s += tmp; }
    }
    __syncthreads();
    int off = gb + x - v + wsum[tid >> 6];
    int node = b * BSZ + tid;
    if (node < NN) {
        rowptr[node] = off;
        dinv[node] = rsqrtf((float)v + 1.0f);
    }
    lcur[tid] = off;
    __syncthreads();
    for (int i = gb + tid; i < ge; i += BSZ) {
        u32 rec = bin[i];
        int pos = atomicAdd(&lcur[rec & (BSZ - 1)], 1);
        csr[pos] = rec >> 9;
    }
}

// ---------------- weight conversion only: Wt[l][c][k] = bf16(Ws[l][k][c]) ----------------
__global__ void k_cvt_w(const float* __restrict__ Ws, u16* __restrict__ Wt) {
    int j = (blockIdx.x * blockDim.x + threadIdx.x) * 4;
    if (j >= NL * CH * CH) return;
    int l = j >> 14, c = (j >> 7) & 127, k = j & 127;  // k multiple of 4
    ushort4 o;
    o.x = f2bf(Ws[(l << 14) + ((k + 0) << 7) + c]);
    o.y = f2bf(Ws[(l << 14) + ((k + 1) << 7) + c]);
    o.z = f2bf(Ws[(l << 14) + ((k + 2) << 7) + c]);
    o.w = f2bf(Ws[(l << 14) + ((k + 3) << 7) + c]);
    *(ushort4*)(Wt + j) = o;
}

// ---------------- MFMA GEMM: out[N,128] = A[N,128] @ W ----------------
// F32IN=1: A is fp32 (layer 0, fused conversion); else A is bf16.
template <int F32IN>
__global__ __launch_bounds__(256) void k_mm_t(const void* __restrict__ Ain,
                                              const u16* __restrict__ Wt,
                                              u16* __restrict__ out) {
    int tid = threadIdx.x;
    int lane = tid & 63;
    int wv = tid >> 6;
    int rbase = blockIdx.x * 128 + wv * 32;
    int lm = lane & 15;
    int lk = (lane >> 4) << 3;

    f4 acc[2][8];
#pragma unroll
    for (int m = 0; m < 2; ++m)
#pragma unroll
        for (int n = 0; n < 8; ++n) acc[m][n] = (f4){0.f, 0.f, 0.f, 0.f};

    int r0 = rbase + lm;      if (r0 >= NN) r0 = NN - 1;
    int r1 = rbase + 16 + lm; if (r1 >= NN) r1 = NN - 1;

#pragma unroll
    for (int kk = 0; kk < 4; ++kk) {
        int ko = kk * 32 + lk;
        bf8 a0, a1;
        if (F32IN) {
            const float* A = (const float*)Ain;
            float4 p0 = *(const float4*)(A + (size_t)r0 * CH + ko);
            float4 q0 = *(const float4*)(A + (size_t)r0 * CH + ko + 4);
            float4 p1 = *(const float4*)(A + (size_t)r1 * CH + ko);
            float4 q1 = *(const float4*)(A + (size_t)r1 * CH + ko + 4);
            a0[0] = (short)f2bf(p0.x); a0[1] = (short)f2bf(p0.y);
            a0[2] = (short)f2bf(p0.z); a0[3] = (short)f2bf(p0.w);
            a0[4] = (short)f2bf(q0.x); a0[5] = (short)f2bf(q0.y);
            a0[6] = (short)f2bf(q0.z); a0[7] = (short)f2bf(q0.w);
            a1[0] = (short)f2bf(p1.x); a1[1] = (short)f2bf(p1.y);
            a1[2] = (short)f2bf(p1.z); a1[3] = (short)f2bf(p1.w);
            a1[4] = (short)f2bf(q1.x); a1[5] = (short)f2bf(q1.y);
            a1[6] = (short)f2bf(q1.z); a1[7] = (short)f2bf(q1.w);
        } else {
            const u16* A = (const u16*)Ain;
            a0 = *(const bf8*)(A + (size_t)r0 * CH + ko);
            a1 = *(const bf8*)(A + (size_t)r1 * CH + ko);
        }
#pragma unroll
        for (int n = 0; n < 8; ++n) {
            bf8 b = *(const bf8*)(Wt + (n * 16 + lm) * CH + ko);
            acc[0][n] = __builtin_amdgcn_mfma_f32_16x16x32_bf16(a0, b, acc[0][n], 0, 0, 0);
            acc[1][n] = __builtin_amdgcn_mfma_f32_16x16x32_bf16(a1, b, acc[1][n], 0, 0, 0);
        }
    }

#pragma unroll
    for (int m = 0; m < 2; ++m) {
        int rb = rbase + m * 16 + (lane >> 4) * 4;
#pragma unroll
        for (int r = 0; r < 4; ++r) {
            int row = rb + r;
            if (row < NN) {
#pragma unroll
                for (int n = 0; n < 8; ++n)
                    out[(size_t)row * CH + n * 16 + lm] = f2bf(acc[m][n][r]);
            }
        }
    }
}

// ---------------- aggregation: 16-lane group per node, 8-deep MLP ----------------
#define ACC8W(v, w) \
    acc[0] = fmaf(bflo(v[0]), w, acc[0]); acc[1] = fmaf(bfhi(v[0]), w, acc[1]); \
    acc[2] = fmaf(bflo(v[1]), w, acc[2]); acc[3] = fmaf(bfhi(v[1]), w, acc[3]); \
    acc[4] = fmaf(bflo(v[2]), w, acc[4]); acc[5] = fmaf(bfhi(v[2]), w, acc[5]); \
    acc[6] = fmaf(bflo(v[3]), w, acc[6]); acc[7] = fmaf(bfhi(v[3]), w, acc[7]);

__global__ __launch_bounds__(256) void k_aggr(const u16* __restrict__ t,
                                              const int* __restrict__ rowptr,
                                              const u32* __restrict__ csr,
                                              const float* __restrict__ dinv,
                                              const float* __restrict__ b,
                                              u16* __restrict__ h,
                                              const float* __restrict__ hw,
                                              float* __restrict__ partial) {
    int node = blockIdx.x * 16 + (threadIdx.x >> 4);
    if (node >= NN) return;
    int l16 = threadIdx.x & 15;
    int c8 = l16 << 3;
    const u32x4* tp = (const u32x4*)t;

    int beg = rowptr[node], end = rowptr[node + 1];
    float dn = dinv[node];
    float acc[8];
#pragma unroll
    for (int k = 0; k < 8; ++k) acc[k] = 0.f;

    int j = beg;
    for (; j + 8 <= end; j += 8) {
        int s0 = (int)csr[j],     s1 = (int)csr[j + 1];
        int s2 = (int)csr[j + 2], s3 = (int)csr[j + 3];
        int s4 = (int)csr[j + 4], s5 = (int)csr[j + 5];
        int s6 = (int)csr[j + 6], s7 = (int)csr[j + 7];
        float w0 = dinv[s0], w1 = dinv[s1], w2 = dinv[s2], w3 = dinv[s3];
        float w4 = dinv[s4], w5 = dinv[s5], w6 = dinv[s6], w7 = dinv[s7];
        u32x4 v0 = tp[s0 * 16 + l16];
        u32x4 v1 = tp[s1 * 16 + l16];
        u32x4 v2 = tp[s2 * 16 + l16];
        u32x4 v3 = tp[s3 * 16 + l16];
        u32x4 v4 = tp[s4 * 16 + l16];
        u32x4 v5 = tp[s5 * 16 + l16];
        u32x4 v6 = tp[s6 * 16 + l16];
        u32x4 v7 = tp[s7 * 16 + l16];
        ACC8W(v0, w0); ACC8W(v1, w1); ACC8W(v2, w2); ACC8W(v3, w3);
        ACC8W(v4, w4); ACC8W(v5, w5); ACC8W(v6, w6); ACC8W(v7, w7);
    }
    for (; j + 4 <= end; j += 4) {
        int s0 = (int)csr[j], s1 = (int)csr[j + 1];
        int s2 = (int)csr[j + 2], s3 = (int)csr[j + 3];
        float w0 = dinv[s0], w1 = dinv[s1], w2 = dinv[s2], w3 = dinv[s3];
        u32x4 v0 = tp[s0 * 16 + l16];
        u32x4 v1 = tp[s1 * 16 + l16];
        u32x4 v2 = tp[s2 * 16 + l16];
        u32x4 v3 = tp[s3 * 16 + l16];
        ACC8W(v0, w0); ACC8W(v1, w1); ACC8W(v2, w2); ACC8W(v3, w3);
    }
    for (; j < end; ++j) {
        int s = (int)csr[j];
        float w = dinv[s];
        u32x4 v = tp[s * 16 + l16];
        ACC8W(v, w);
    }

    u32x4 sv = tp[node * 16 + l16];
    float4 b0 = *(const float4*)(b + c8);
    float4 b1 = *(const float4*)(b + c8 + 4);
    float r[8];
    r[0] = fmaxf(fmaf(fmaf(bflo(sv[0]), dn, acc[0]), dn, b0.x), 0.f);
    r[1] = fmaxf(fmaf(fmaf(bfhi(sv[0]), dn, acc[1]), dn, b0.y), 0.f);
    r[2] = fmaxf(fmaf(fmaf(bflo(sv[1]), dn, acc[2]), dn, b0.z), 0.f);
    r[3] = fmaxf(fmaf(fmaf(bfhi(sv[1]), dn, acc[3]), dn, b0.w), 0.f);
    r[4] = fmaxf(fmaf(fmaf(bflo(sv[2]), dn, acc[4]), dn, b1.x), 0.f);
    r[5] = fmaxf(fmaf(fmaf(bfhi(sv[2]), dn, acc[5]), dn, b1.y), 0.f);
    r[6] = fmaxf(fmaf(fmaf(bflo(sv[3]), dn, acc[6]), dn, b1.z), 0.f);
    r[7] = fmaxf(fmaf(fmaf(bfhi(sv[3]), dn, acc[7]), dn, b1.w), 0.f);

    if (hw) {
        float4 w0 = *(const float4*)(hw + c8);
        float4 w1 = *(const float4*)(hw + c8 + 4);
        float d = r[0] * w0.x + r[1] * w0.y + r[2] * w0.z + r[3] * w0.w
                + r[4] * w1.x + r[5] * w1.y + r[6] * w1.z + r[7] * w1.w;
#pragma unroll
        for (int off = 8; off > 0; off >>= 1) d += __shfl_xor(d, off);
        if (l16 == 0) partial[node] = d;
    } else {
        u32x4 o;
        o[0] = ((u32)f2bf(r[1]) << 16) | (u32)f2bf(r[0]);
        o[1] = ((u32)f2bf(r[3]) << 16) | (u32)f2bf(r[2]);
        o[2] = ((u32)f2bf(r[5]) << 16) | (u32)f2bf(r[4]);
        o[3] = ((u32)f2bf(r[7]) << 16) | (u32)f2bf(r[6]);
        ((u32x4*)h)[node * 16 + l16] = o;
    }
}

// ---------------- head ----------------

__device__ __forceinline__ int lbound(const void* bt, bool is64, int target) {
    int lo = 0, hi = NN;
    while (lo < hi) {
        int mid = (lo + hi) >> 1;
        long long v = ld_idx(bt, mid, is64);
        if (v < (long long)target) lo = mid + 1; else hi = mid;
    }
    return lo;
}

__global__ __launch_bounds__(256) void k_head(const float* __restrict__ partial,
                                              const void* __restrict__ batch,
                                              const int* __restrict__ flags,
                                              const float* __restrict__ hb,
                                              float* __restrict__ out) {
    int g = blockIdx.x * 4 + (threadIdx.x >> 6);
    if (g >= NG) return;
    int lane = threadIdx.x & 63;
    bool is64 = (flags[1] == 0);
    int lo = lbound(batch, is64, g);
    int hi = lbound(batch, is64, g + 1);
    float s = 0.f;
    for (int i = lo + lane; i < hi; i += 64) s += partial[i];
#pragma unroll
    for (int off = 32; off > 0; off >>= 1) s += __shfl_down(s, off);
    if (lane == 0) out[g] = s + hb[0];
}

extern "C" void kernel_launch(void* const* d_in, const int* in_sizes, int n_in,
                              void* d_out, int out_size, void* d_ws, size_t ws_size,
                              hipStream_t stream) {
    const float* x  = (const float*)d_in[0];
    const void*  ei = d_in[1];
    const void*  bt = d_in[2];
    const float* Ws = (const float*)d_in[3];
    const float* bs = (const float*)d_in[4];
    const float* hw = (const float*)d_in[5];
    const float* hb = (const float*)d_in[6];
    float* out = (float*)d_out;

    char* ws = (char*)d_ws;
    size_t p = 0;
    auto alloc = [&](size_t bytes) { size_t r = p; p += (bytes + 255) & ~(size_t)255; return r; };
    size_t o_flags  = alloc(256);
    size_t o_dinv   = alloc((size_t)NN * 4);
    size_t o_rowptr = alloc((size_t)(NN + 1) * 4);
    size_t o_bcnt   = alloc((size_t)NBUK * 4);
    size_t o_gbase  = alloc((size_t)(NBUK + 1) * 4);
    size_t o_gcur   = alloc((size_t)NBUK * 4);
    size_t o_part   = alloc((size_t)NN * 4);
    size_t o_bin    = alloc((size_t)NE * 4);
    size_t o_csr    = alloc((size_t)NE * 4);
    size_t o_tb     = alloc((size_t)NN * CH * 2);
    size_t o_hb     = alloc((size_t)NN * CH * 2);
    size_t o_wt     = alloc((size_t)NL * CH * CH * 2);
    (void)ws_size;  // ~28 MB

    int*   flags  = (int*)(ws + o_flags);
    float* dinv   = (float*)(ws + o_dinv);
    int*   rowptr = (int*)(ws + o_rowptr);
    int*   bcnt   = (int*)(ws + o_bcnt);
    int*   gbase  = (int*)(ws + o_gbase);
    int*   gcur   = (int*)(ws + o_gcur);
    float* part   = (float*)(ws + o_part);
    u32*   bin    = (u32*)(ws + o_bin);
    u32*   csr    = (u32*)(ws + o_csr);
    u16*   tb     = (u16*)(ws + o_tb);
    u16*   hbuf   = (u16*)(ws + o_hb);
    u16*   Wt     = (u16*)(ws + o_wt);

    k_zero<<<1, 256, 0, stream>>>(bcnt, flags);
    k_detect<<<256, 256, 0, stream>>>((const int*)ei, (const int*)bt, flags);
    k_hist<<<(NE + TILE - 1) / TILE, 256, 0, stream>>>(ei, flags, bcnt);
    k_bscan<<<1, 256, 0, stream>>>(bcnt, gbase, gcur, rowptr);
    k_bin<<<(NE + TILE - 1) / TILE, 256, 0, stream>>>(ei, flags, gcur, bin);
    k_fillc<<<NBUK, BSZ, 0, stream>>>(bin, gbase, rowptr, dinv, csr);
    k_cvt_w<<<(NL * CH * CH / 4 + 255) / 256, 256, 0, stream>>>(Ws, Wt);

    const void* hin = (const void*)x;
    for (int l = 0; l < NL; ++l) {
        bool last = (l == NL - 1);
        if (l == 0)
            k_mm_t<1><<<(NN + 127) / 128, 256, 0, stream>>>(hin, Wt, tb);
        else
            k_mm_t<0><<<(NN + 127) / 128, 256, 0, stream>>>(hin, Wt + (size_t)l * CH * CH, tb);
        k_aggr<<<(NN + 15) / 16, 256, 0, stream>>>(tb, rowptr, csr, dinv,
                                                   bs + (size_t)l * CH, hbuf,
                                                   last ? hw : nullptr, part);
        hin = (const void*)hbuf;
    }

    k_head<<<(NG + 3) / 4, 256, 0, stream>>>(part, bt, flags, hb, out);
}